// Round 13
// 267.710 us; speedup vs baseline: 19.2260x; 1.1139x over previous
//
#include <hip/hip_runtime.h>
#include <math.h>

#define TPB 256

typedef __attribute__((ext_vector_type(8))) short bf16x8;
typedef __attribute__((ext_vector_type(4))) float f32x4;

__device__ __forceinline__ float gelu_exact(float x) {
    return 0.5f * x * (1.0f + erff(x * 0.70710678118654752f));
}

__device__ __forceinline__ unsigned short f2bf(float x) {
    unsigned u = __float_as_uint(x);
    return (unsigned short)((u + 0x7fffu + ((u >> 16) & 1u)) >> 16);
}

// ---------------------------------------------------------------------------
// Stage-A instance-norm stats (x + pos broadcast), 2048 channels.
// ---------------------------------------------------------------------------
__global__ void k_stats_cm(const float* __restrict__ x0, const float* __restrict__ x1,
                           const float* __restrict__ pos, float* __restrict__ mean,
                           float* __restrict__ rstd) {
    int gc = blockIdx.x;
    const float* src = ((gc < 1024) ? x0 : x1) + (size_t)(gc & 1023) * 4096;
    const float* posr = pos + (size_t)(gc & 127) * 4096;
    float s = 0.f, s2 = 0.f;
    for (int p = threadIdx.x; p < 4096; p += TPB) {
        float v = src[p] + posr[p];
        s += v; s2 += v * v;
    }
#pragma unroll
    for (int m = 32; m; m >>= 1) { s += __shfl_xor(s, m); s2 += __shfl_xor(s2, m); }
    __shared__ float ls[4], ls2[4];
    int w = threadIdx.x >> 6;
    if ((threadIdx.x & 63) == 0) { ls[w] = s; ls2[w] = s2; }
    __syncthreads();
    if (threadIdx.x == 0) {
        s = ls[0] + ls[1] + ls[2] + ls[3];
        s2 = ls2[0] + ls2[1] + ls2[2] + ls2[3];
        float mu = s / 4096.f;
        float var = s2 / 4096.f - mu * mu;
        mean[gc] = mu;
        rstd[gc] = rsqrtf(var + 1e-5f);
    }
}

// ---------------------------------------------------------------------------
// Token-major stats reduces.
// ---------------------------------------------------------------------------
__global__ void k_stats_red(const float* __restrict__ part, float* __restrict__ mean,
                            float* __restrict__ rstd, int nc, int T) {
    int b = blockIdx.x, d = threadIdx.x;
    float s = 0.f, s2 = 0.f;
    for (int c = 0; c < nc; c++) {
        const float* p = part + ((size_t)(b * nc + c) * 2) * 128;
        s += p[d]; s2 += p[128 + d];
    }
    float mu = s / (float)T;
    float var = s2 / (float)T - mu * mu;
    mean[b * 128 + d] = mu;
    rstd[b * 128 + d] = rsqrtf(var + 1e-5f);
}

__global__ void k_stats_red2(const float* __restrict__ part,
                             float* __restrict__ meanC, float* __restrict__ rstdC,
                             float* __restrict__ meanL, float* __restrict__ rstdL) {
    int idx = blockIdx.x, d = threadIdx.x;
    int sel = idx >> 3, b = idx & 7;
    float s = 0.f, s2 = 0.f;
    for (int c = 0; c < 32; c++) {
        const float* p = part + ((size_t)((sel * 8 + b) * 32 + c) * 2) * 128;
        s += p[d]; s2 += p[128 + d];
    }
    float mu = s / 2048.f;
    float var = s2 / 2048.f - mu * mu;
    float* mean = sel ? meanL : meanC;
    float* rstd = sel ? rstdL : rstdC;
    mean[b * 128 + d] = mu;
    rstd[b * 128 + d] = rsqrtf(var + 1e-5f);
}

// ---------------------------------------------------------------------------
// Conv prep (cam+lid merged): normalize+ReLU+im2col -> bf16 xcolT[bb][p][512].
// ---------------------------------------------------------------------------
__global__ void k_prep(const float* __restrict__ cam, const float* __restrict__ lid,
                       const float* __restrict__ pos, const float* __restrict__ mean,
                       const float* __restrict__ rstd, unsigned short* __restrict__ xcolT) {
    __shared__ unsigned short T[32 * 520];
    int h = blockIdx.x, bb = blockIdx.y;
    int b = bb & 7, so = (bb < 8) ? 0 : 1024;
    const float* x = (bb < 8) ? cam : lid;
    int tid = threadIdx.x;
    for (int i = tid; i < 4096; i += TPB) {
        int c = i >> 5, w = i & 31;
        int ch = b * 128 + c;
        const float* xr = x + (size_t)ch * 4096 + (2 * h) * 64 + 2 * w;
        const float* pr = pos + (size_t)c * 4096 + (2 * h) * 64 + 2 * w;
        float mu = mean[so + ch], rs = rstd[so + ch];
        float2 x0 = *(const float2*)xr;
        float2 x1 = *(const float2*)(xr + 64);
        float2 p0 = *(const float2*)pr;
        float2 p1 = *(const float2*)(pr + 64);
        ushort4 u;
        u.x = f2bf(fmaxf((x0.x + p0.x - mu) * rs, 0.f));
        u.y = f2bf(fmaxf((x0.y + p0.y - mu) * rs, 0.f));
        u.z = f2bf(fmaxf((x1.x + p1.x - mu) * rs, 0.f));
        u.w = f2bf(fmaxf((x1.y + p1.y - mu) * rs, 0.f));
        *(ushort4*)&T[w * 520 + c * 4] = u;
    }
    __syncthreads();
    unsigned short* dst = xcolT + ((size_t)bb * 1024 + h * 32) * 512;
    for (int i = tid; i < 2048; i += TPB) {
        int w = i >> 6, kk = (i & 63) * 8;
        *(bf16x8*)&dst[(size_t)w * 512 + kk] = *(bf16x8*)&T[w * 520 + kk];
    }
}

// ---------------------------------------------------------------------------
// Conv as batched MFMA GEMM (cam+lid merged) + per-token LN stats epilogue.
// grid (16, 1, 16).
// ---------------------------------------------------------------------------
__global__ __launch_bounds__(256, 2) void k_conv_gemm(
        const float* __restrict__ W, const unsigned short* __restrict__ xcolT,
        float* __restrict__ camT, float* __restrict__ lidT,
        float* __restrict__ mean_e, float* __restrict__ rstd_e) {
    __shared__ __align__(16) unsigned short As[128 * 40];
    __shared__ __align__(16) unsigned short Bs[64 * 40];
    __shared__ float red[2048];
    int tid = threadIdx.x, lane = tid & 63, w = tid >> 6;
    int l16 = lane & 15, lhi = lane >> 4;
    int n0 = blockIdx.x * 64, bb = blockIdx.z;
    const unsigned short* BT = xcolT + (size_t)bb * 524288;
    float* eT = ((bb < 8) ? camT : lidT) + (size_t)(bb & 7) * 131072;

    f32x4 acc[2][4];
#pragma unroll
    for (int mi = 0; mi < 2; mi++)
#pragma unroll
        for (int ni = 0; ni < 4; ni++) acc[mi][ni] = (f32x4){0.f, 0.f, 0.f, 0.f};

    for (int k0 = 0; k0 < 512; k0 += 32) {
        for (int i = tid; i < 1024; i += TPB) {
            int row = i >> 3, kc = (i & 7) * 4;
            float4 va = *(const float4*)&W[(size_t)row * 512 + k0 + kc];
            ushort4 u;
            u.x = f2bf(va.x); u.y = f2bf(va.y); u.z = f2bf(va.z); u.w = f2bf(va.w);
            *(ushort4*)&As[row * 40 + kc] = u;
        }
        for (int i = tid; i < 256; i += TPB) {
            int n = i >> 2, kc = (i & 3) * 8;
            *(bf16x8*)&Bs[n * 40 + kc] = *(const bf16x8*)&BT[(size_t)(n0 + n) * 512 + k0 + kc];
        }
        __syncthreads();
        bf16x8 af[2], bfr[4];
#pragma unroll
        for (int mi = 0; mi < 2; mi++)
            af[mi] = *(bf16x8*)&As[(w * 32 + mi * 16 + l16) * 40 + lhi * 8];
#pragma unroll
        for (int ni = 0; ni < 4; ni++)
            bfr[ni] = *(bf16x8*)&Bs[(ni * 16 + l16) * 40 + lhi * 8];
#pragma unroll
        for (int mi = 0; mi < 2; mi++)
#pragma unroll
            for (int ni = 0; ni < 4; ni++)
                acc[mi][ni] = __builtin_amdgcn_mfma_f32_16x16x32_bf16(af[mi], bfr[ni], acc[mi][ni], 0, 0, 0);
        __syncthreads();
    }
#pragma unroll
    for (int mi = 0; mi < 2; mi++)
#pragma unroll
        for (int ni = 0; ni < 4; ni++) {
            int col = n0 + ni * 16 + l16;
            int rowb = w * 32 + mi * 16 + lhi * 4;
            *(float4*)&eT[(size_t)col * 128 + rowb] = *(float4*)&acc[mi][ni];
        }
#pragma unroll
    for (int ni = 0; ni < 4; ni++) {
        float s = 0.f, s2 = 0.f;
#pragma unroll
        for (int mi = 0; mi < 2; mi++)
#pragma unroll
            for (int rg = 0; rg < 4; rg++) {
                float v = acc[mi][ni][rg];
                s += v; s2 += v * v;
            }
        int idx = (ni * 16 + l16) * 16 + w * 4 + lhi;
        red[idx] = s;
        red[1024 + idx] = s2;
    }
    __syncthreads();
    if (tid < 64) {
        int ni = tid >> 4, c16 = tid & 15;
        float s = 0.f, s2 = 0.f;
#pragma unroll
        for (int j = 0; j < 16; j++) {
            s += red[(ni * 16 + c16) * 16 + j];
            s2 += red[1024 + (ni * 16 + c16) * 16 + j];
        }
        int col = n0 + ni * 16 + c16;
        int tok = bb * 1024 + col;
        float mu = s * (1.f / 128.f);
        float var = s2 * (1.f / 128.f) - mu * mu;
        mean_e[tok] = mu;
        rstd_e[tok] = rsqrtf(var + 1e-5f);
    }
}

// ---------------------------------------------------------------------------
// Weight transposes (bid<384, gamma-prescaled Q/K/V) + beta@W bias vectors
// (bid 384..389) in ONE launch. grid 390.
// ---------------------------------------------------------------------------
__global__ void k_wtrans_all(
        const float* __restrict__ wq, const float* __restrict__ wk,
        const float* __restrict__ wv, const float* __restrict__ proj,
        const float* __restrict__ m1, const float* __restrict__ m2,
        const float* __restrict__ ct,
        const float* __restrict__ gq, const float* __restrict__ gk,
        const float* __restrict__ gv,
        const float* __restrict__ bq_in, const float* __restrict__ bk_in,
        const float* __restrict__ bv_in,
        unsigned short* wqT, unsigned short* wkT, unsigned short* wvT,
        unsigned short* projT, unsigned short* m1T, unsigned short* m2T,
        unsigned short* ctT, float* __restrict__ bout) {
    __shared__ float t[32][33];
    int bid = blockIdx.x;
    int tid = threadIdx.x;
    if (bid >= 384) {
        int i = bid - 384;
        int which = i >> 1, half = i & 1;
        const float* W = (which == 0) ? wq : (which == 1) ? wk : wv;
        const float* bb = (which == 0) ? bq_in : (which == 1) ? bk_in : bv_in;
        int n = half * 256 + tid;
        float s = 0.f;
        for (int k = 0; k < 128; k++) s += bb[k] * W[(size_t)k * 512 + n];
        bout[which * 512 + n] = s;
        return;
    }
    const float* W; unsigned short* WT; const float* sc = nullptr; int K, N, ti;
    if (bid < 64)       { W = wq;   WT = wqT;   sc = gq; K = 128; N = 512; ti = bid; }
    else if (bid < 128) { W = wk;   WT = wkT;   sc = gk; K = 128; N = 512; ti = bid - 64; }
    else if (bid < 192) { W = wv;   WT = wvT;   sc = gv; K = 128; N = 512; ti = bid - 128; }
    else if (bid < 256) { W = proj; WT = projT; K = 512; N = 128; ti = bid - 192; }
    else if (bid < 288) { W = m1;   WT = m1T;   K = 128; N = 256; ti = bid - 256; }
    else if (bid < 320) { W = m2;   WT = m2T;   K = 256; N = 128; ti = bid - 288; }
    else                { W = ct;   WT = ctT;   K = 128; N = 512; ti = bid - 320; }
    int tx = N >> 5;
    int n0 = (ti % tx) * 32, k0 = (ti / tx) * 32;
    for (int i = tid; i < 1024; i += TPB) {
        int r = i >> 5, c = i & 31;
        float v = W[(size_t)(k0 + r) * N + n0 + c];
        if (sc) v *= sc[k0 + r];
        t[r][c] = v;
    }
    __syncthreads();
    for (int i = tid; i < 1024; i += TPB) {
        int r = i >> 5, c = i & 31;
        WT[(size_t)(n0 + r) * K + k0 + c] = f2bf(t[c][r]);
    }
}

// ---------------------------------------------------------------------------
// Merged Q/K/V projection GEMM with fused LN on A. grid (12, 128).
// ---------------------------------------------------------------------------
__global__ __launch_bounds__(256, 2) void k_qkv_gemm(
        const float* __restrict__ camT, const float* __restrict__ lidT,
        const float* __restrict__ me, const float* __restrict__ re,
        const unsigned short* __restrict__ wqT, const unsigned short* __restrict__ wkT,
        const unsigned short* __restrict__ wvT,
        unsigned short* __restrict__ qout, unsigned short* __restrict__ kout,
        unsigned short* __restrict__ vout,
        const float* __restrict__ bvecs, float qscale) {
    __shared__ __align__(16) unsigned short As[128 * 40];
    __shared__ __align__(16) unsigned short Bs[128 * 40];
    int tid = threadIdx.x, lane = tid & 63, w = tid >> 6;
    int l16 = lane & 15, lhi = lane >> 4;
    int wm = w >> 1, wn = w & 1;
    int which = blockIdx.x >> 2;
    int n0 = (blockIdx.x & 3) * 128;
    int m0 = blockIdx.y * 128;
    const unsigned short* BT = (which == 0) ? wqT : (which == 1) ? wkT : wvT;
    const float* bias = bvecs + which * 512;

    f32x4 acc[4][4];
#pragma unroll
    for (int mi = 0; mi < 4; mi++)
#pragma unroll
        for (int ni = 0; ni < 4; ni++) acc[mi][ni] = (f32x4){0.f, 0.f, 0.f, 0.f};

    for (int k0 = 0; k0 < 128; k0 += 32) {
        for (int i = tid; i < 1024; i += TPB) {
            int row = i >> 3, kc = (i & 7) * 4;
            int r = m0 + row;
            const float* srow;
            int tok;
            if (which == 0) {
                int b = r >> 11, t = r & 2047;
                bool cam = t < 1024;
                tok = (cam ? b : 8 + b) * 1024 + (t & 1023);
                srow = (cam ? camT : lidT) + (size_t)(b * 1024 + (t & 1023)) * 128;
            } else {
                tok = r;
                srow = ((r < 8192) ? camT : lidT) + (size_t)(r & 8191) * 128;
            }
            float mu = me[tok], rs = re[tok];
            float4 va = *(const float4*)&srow[k0 + kc];
            ushort4 u;
            u.x = f2bf((va.x - mu) * rs); u.y = f2bf((va.y - mu) * rs);
            u.z = f2bf((va.z - mu) * rs); u.w = f2bf((va.w - mu) * rs);
            *(ushort4*)&As[row * 40 + kc] = u;
        }
        for (int i = tid; i < 512; i += TPB) {
            int n = i >> 2, kc = (i & 3) * 8;
            *(bf16x8*)&Bs[n * 40 + kc] = *(const bf16x8*)&BT[(size_t)(n0 + n) * 128 + k0 + kc];
        }
        __syncthreads();
        bf16x8 af[4], bfr[4];
#pragma unroll
        for (int mi = 0; mi < 4; mi++)
            af[mi] = *(bf16x8*)&As[(wm * 64 + mi * 16 + l16) * 40 + lhi * 8];
#pragma unroll
        for (int ni = 0; ni < 4; ni++)
            bfr[ni] = *(bf16x8*)&Bs[(wn * 64 + ni * 16 + l16) * 40 + lhi * 8];
#pragma unroll
        for (int mi = 0; mi < 4; mi++)
#pragma unroll
            for (int ni = 0; ni < 4; ni++)
                acc[mi][ni] = __builtin_amdgcn_mfma_f32_16x16x32_bf16(af[mi], bfr[ni], acc[mi][ni], 0, 0, 0);
        __syncthreads();
    }
#pragma unroll
    for (int mi = 0; mi < 4; mi++) {
#pragma unroll
        for (int ni = 0; ni < 4; ni++) {
            int col = n0 + wn * 64 + ni * 16 + l16;
            float bc = bias[col];
            if (which == 2) {
                int row0 = m0 + wm * 64 + mi * 16 + lhi * 4;
                int bb = row0 >> 10, t0 = row0 & 1023;
                ushort4 u;
                u.x = f2bf(acc[mi][ni][0] + bc); u.y = f2bf(acc[mi][ni][1] + bc);
                u.z = f2bf(acc[mi][ni][2] + bc); u.w = f2bf(acc[mi][ni][3] + bc);
                *(ushort4*)&vout[(((size_t)(bb * 4 + (col >> 7))) * 128 + (col & 127)) * 1024 + t0] = u;
            } else {
                int sT = (which == 0) ? 11 : 10;
                float sc = (which == 0) ? qscale : 1.f;
                unsigned short* C16 = (which == 0) ? qout : kout;
#pragma unroll
                for (int rg = 0; rg < 4; rg++) {
                    int row = m0 + wm * 64 + mi * 16 + lhi * 4 + rg;
                    int bb = row >> sT, t = row & ((1 << sT) - 1);
                    size_t oa = ((((size_t)bb * 4 + (col >> 7)) << sT) + t) * 128 + (col & 127);
                    C16[oa] = f2bf((acc[mi][ni][rg] + bc) * sc);
                }
            }
        }
    }
}

// ---------------------------------------------------------------------------
// FUSED TAIL: proj(K=512)+bias+skip -> preLN (kept in registers!) ->
// mlp1(K=128)+GELU -> mlp2(K=256)+residual(LN'd z) -> postLN -> z out + stats.
// Operand-swapped MFMA: lane holds one token (l16) x 4-consecutive-cols.
// grid 512 x 256 thr; 64 tokens/block. LDS 43 KB (phase-overlaid).
// ---------------------------------------------------------------------------
__global__ __launch_bounds__(256, 2) void k_tail_fused(
        const unsigned short* __restrict__ abuf, const unsigned short* __restrict__ projT,
        const unsigned short* __restrict__ m1T, const unsigned short* __restrict__ m2T,
        const float* __restrict__ camT, const float* __restrict__ lidT,
        const float* __restrict__ proj_b,
        const float* __restrict__ pre_g, const float* __restrict__ pre_b,
        const float* __restrict__ mlp_b1, const float* __restrict__ mlp_b2,
        const float* __restrict__ post_g, const float* __restrict__ post_b,
        float* __restrict__ z_cam, float* __restrict__ z_lid,
        float* __restrict__ part) {
    __shared__ __align__(16) unsigned short shm[21504];  // 43 KB
    int tid = threadIdx.x, lane = tid & 63, w = tid >> 6;
    int l16 = lane & 15, lhi = lane >> 4;
    int m0 = blockIdx.x * 64;
    int tok = w * 16 + l16;
    int grow = m0 + tok;
    int tsw = tok & 7;

    // ---- Phase 1: proj GEMM (K=512), swapped: D[col n][tok] ----
    unsigned short* Ts = shm;          // [64][40]
    unsigned short* Ws = shm + 2560;   // [128][40]
    f32x4 z2[8];
#pragma unroll
    for (int ni = 0; ni < 8; ni++) z2[ni] = (f32x4){0.f, 0.f, 0.f, 0.f};
    for (int k0 = 0; k0 < 512; k0 += 32) {
        for (int i = tid; i < 256; i += TPB) {
            int row = i >> 2, kc = (i & 3) * 8;
            *(bf16x8*)&Ts[row * 40 + kc] =
                *(const bf16x8*)&abuf[(size_t)(m0 + row) * 512 + k0 + kc];
        }
        for (int i = tid; i < 512; i += TPB) {
            int row = i >> 2, kc = (i & 3) * 8;
            *(bf16x8*)&Ws[row * 40 + kc] =
                *(const bf16x8*)&projT[(size_t)row * 512 + k0 + kc];
        }
        __syncthreads();
        bf16x8 bfr = *(bf16x8*)&Ts[tok * 40 + lhi * 8];
#pragma unroll
        for (int ni = 0; ni < 8; ni++) {
            bf16x8 af = *(bf16x8*)&Ws[(ni * 16 + l16) * 40 + lhi * 8];
            z2[ni] = __builtin_amdgcn_mfma_f32_16x16x32_bf16(af, bfr, z2[ni], 0, 0, 0);
        }
        __syncthreads();
    }
    // epilogue 1: + proj_b + skip (width-concat [camT|lidT])
    {
        int rr = grow & 16383;
        int b = rr >> 11, ss = rr & 2047;
        int Hh = ss >> 6, Ww = ss & 63;
        const float* sp = ((Ww < 32) ? camT : lidT)
                        + ((size_t)(b * 1024 + Hh * 32 + (Ww & 31))) * 128;
#pragma unroll
        for (int ni = 0; ni < 8; ni++) {
            int c0 = ni * 16 + lhi * 4;
            float4 pb = *(const float4*)&proj_b[c0];
            float4 sk = *(const float4*)&sp[c0];
            z2[ni][0] += pb.x + sk.x; z2[ni][1] += pb.y + sk.y;
            z2[ni][2] += pb.z + sk.z; z2[ni][3] += pb.w + sk.w;
        }
    }
    // preLN (in-register): z2 <- LN(z2)  [the LN'd value IS the MLP residual]
    unsigned short* z2ln = shm;  // [64][128] swizzled (overwrites Ts/Ws)
    {
        float s = 0.f, s2 = 0.f;
#pragma unroll
        for (int ni = 0; ni < 8; ni++)
#pragma unroll
            for (int rg = 0; rg < 4; rg++) { float v = z2[ni][rg]; s += v; s2 += v * v; }
        s += __shfl_xor(s, 16); s2 += __shfl_xor(s2, 16);
        s += __shfl_xor(s, 32); s2 += __shfl_xor(s2, 32);
        float mu = s * (1.f / 128.f);
        float var = s2 * (1.f / 128.f) - mu * mu;
        float rs = rsqrtf(var + 1e-5f);
#pragma unroll
        for (int ni = 0; ni < 8; ni++) {
            int c0 = ni * 16 + lhi * 4;
            float4 gg = *(const float4*)&pre_g[c0];
            float4 bb = *(const float4*)&pre_b[c0];
            z2[ni][0] = (z2[ni][0] - mu) * rs * gg.x + bb.x;
            z2[ni][1] = (z2[ni][1] - mu) * rs * gg.y + bb.y;
            z2[ni][2] = (z2[ni][2] - mu) * rs * gg.z + bb.z;
            z2[ni][3] = (z2[ni][3] - mu) * rs * gg.w + bb.w;
            unsigned u01, u23;
            asm("v_cvt_pk_bf16_f32 %0, %1, %2" : "=v"(u01) : "v"(z2[ni][0]), "v"(z2[ni][1]));
            asm("v_cvt_pk_bf16_f32 %0, %1, %2" : "=v"(u23) : "v"(z2[ni][2]), "v"(z2[ni][3]));
            int slot = ni * 2 + (lhi >> 1);
            int base = tok * 128 + ((slot ^ tsw) << 3) + (lhi & 1) * 4;
            *(unsigned*)&z2ln[base] = u01;
            *(unsigned*)&z2ln[base + 2] = u23;
        }
    }

    // ---- Phase 2: mlp1 (K=128, N=256), swapped ----
    unsigned short* As1 = shm + 8192;  // [256][40]
    f32x4 a1[16];
#pragma unroll
    for (int ni = 0; ni < 16; ni++) a1[ni] = (f32x4){0.f, 0.f, 0.f, 0.f};
    for (int ks = 0; ks < 4; ks++) {
        int k0 = ks * 32;
        for (int i = tid; i < 1024; i += TPB) {
            int row = i >> 2, kc = (i & 3) * 8;
            *(bf16x8*)&As1[row * 40 + kc] =
                *(const bf16x8*)&m1T[(size_t)row * 128 + k0 + kc];
        }
        __syncthreads();
        bf16x8 bfr = *(bf16x8*)&z2ln[tok * 128 + (((ks * 4 + lhi) ^ tsw) << 3)];
#pragma unroll
        for (int ni = 0; ni < 16; ni++) {
            bf16x8 af = *(bf16x8*)&As1[(ni * 16 + l16) * 40 + lhi * 8];
            a1[ni] = __builtin_amdgcn_mfma_f32_16x16x32_bf16(af, bfr, a1[ni], 0, 0, 0);
        }
        __syncthreads();
    }
    // GELU -> h1 bf16 to LDS
    unsigned short* Hs = shm;  // [64][256] swizzled (overwrites z2ln/As1)
#pragma unroll
    for (int ni = 0; ni < 16; ni++) {
        int c0 = ni * 16 + lhi * 4;
        float4 bb = *(const float4*)&mlp_b1[c0];
        float h0 = gelu_exact(a1[ni][0] + bb.x);
        float h1v = gelu_exact(a1[ni][1] + bb.y);
        float h2 = gelu_exact(a1[ni][2] + bb.z);
        float h3 = gelu_exact(a1[ni][3] + bb.w);
        unsigned u01, u23;
        asm("v_cvt_pk_bf16_f32 %0, %1, %2" : "=v"(u01) : "v"(h0), "v"(h1v));
        asm("v_cvt_pk_bf16_f32 %0, %1, %2" : "=v"(u23) : "v"(h2), "v"(h3));
        int slot = ni * 2 + (lhi >> 1);
        int base = tok * 256 + ((slot ^ tsw) << 3) + (lhi & 1) * 4;
        *(unsigned*)&Hs[base] = u01;
        *(unsigned*)&Hs[base + 2] = u23;
    }

    // ---- Phase 3: mlp2 (K=256, N=128), swapped ----
    unsigned short* As2 = shm + 16384;  // [128][40]
    f32x4 a2[8];
#pragma unroll
    for (int ni = 0; ni < 8; ni++) a2[ni] = (f32x4){0.f, 0.f, 0.f, 0.f};
    for (int ks = 0; ks < 8; ks++) {
        int k0 = ks * 32;
        for (int i = tid; i < 512; i += TPB) {
            int row = i >> 2, kc = (i & 3) * 8;
            *(bf16x8*)&As2[row * 40 + kc] =
                *(const bf16x8*)&m2T[(size_t)row * 256 + k0 + kc];
        }
        __syncthreads();
        bf16x8 bfr = *(bf16x8*)&Hs[tok * 256 + (((ks * 4 + lhi) ^ tsw) << 3)];
#pragma unroll
        for (int ni = 0; ni < 8; ni++) {
            bf16x8 af = *(bf16x8*)&As2[(ni * 16 + l16) * 40 + lhi * 8];
            a2[ni] = __builtin_amdgcn_mfma_f32_16x16x32_bf16(af, bfr, a2[ni], 0, 0, 0);
        }
        __syncthreads();
    }
    // epilogue 3: + mlp_b2 + LN'd-z2 residual -> postLN -> store + stats
    float* O = (float*)shm;  // [64][132] fp32 (overwrites Hs/As2)
    {
#pragma unroll
        for (int ni = 0; ni < 8; ni++) {
            int c0 = ni * 16 + lhi * 4;
            float4 bb = *(const float4*)&mlp_b2[c0];
            a2[ni][0] += bb.x + z2[ni][0];
            a2[ni][1] += bb.y + z2[ni][1];
            a2[ni][2] += bb.z + z2[ni][2];
            a2[ni][3] += bb.w + z2[ni][3];
        }
        float s = 0.f, s2 = 0.f;
#pragma unroll
        for (int ni = 0; ni < 8; ni++)
#pragma unroll
            for (int rg = 0; rg < 4; rg++) { float v = a2[ni][rg]; s += v; s2 += v * v; }
        s += __shfl_xor(s, 16); s2 += __shfl_xor(s2, 16);
        s += __shfl_xor(s, 32); s2 += __shfl_xor(s2, 32);
        float mu = s * (1.f / 128.f);
        float var = s2 * (1.f / 128.f) - mu * mu;
        float rs = rsqrtf(var + 1e-5f);
        float* Cp = (grow < 16384) ? z_cam : z_lid;
        size_t ro = (size_t)(grow & 16383) * 128;
#pragma unroll
        for (int ni = 0; ni < 8; ni++) {
            int c0 = ni * 16 + lhi * 4;
            float4 gg = *(const float4*)&post_g[c0];
            float4 bb = *(const float4*)&post_b[c0];
            float4 o;
            o.x = (a2[ni][0] - mu) * rs * gg.x + bb.x;
            o.y = (a2[ni][1] - mu) * rs * gg.y + bb.y;
            o.z = (a2[ni][2] - mu) * rs * gg.z + bb.z;
            o.w = (a2[ni][3] - mu) * rs * gg.w + bb.w;
            *(float4*)&Cp[ro + c0] = o;
            *(float4*)&O[tok * 132 + c0] = o;
        }
    }
    __syncthreads();
    if (tid < 128) {
        int col = tid;
        float s = 0.f, s2 = 0.f;
        for (int t = 0; t < 64; t++) {
            float v = O[t * 132 + col];
            s += v; s2 += v * v;
        }
        int sel = (m0 >= 16384) ? 1 : 0;
        int rrg = m0 & 16383;
        int b = rrg >> 11, c = (rrg >> 6) & 31;
        float* p = part + ((size_t)((sel * 8 + b) * 32 + c) * 2) * 128;
        p[col] = s; p[128 + col] = s2;
    }
}

// ---------------------------------------------------------------------------
// ConvTranspose, ALL THREE outputs in one launch. grid (4, 40, 8).
// ---------------------------------------------------------------------------
__global__ __launch_bounds__(256, 2) void k_convt_gemm(
        const float* __restrict__ srcF, const float* __restrict__ srcC,
        const float* __restrict__ srcL, const float* __restrict__ stats,
        const unsigned short* __restrict__ ctT, float* __restrict__ outp) {
    __shared__ __align__(16) unsigned short As[128 * 40];
    __shared__ __align__(16) unsigned short Bs[128 * 40];
    int tid = threadIdx.x, lane = tid & 63, w = tid >> 6;
    int l16 = lane & 15, lhi = lane >> 4;
    int wm = w >> 1, wn = w & 1;
    int my = blockIdx.y, n0 = blockIdx.x * 128, b = blockIdx.z;
    const float* src; const float* mean; const float* rstd; float* out;
    int M, Hin, m0;
    if (my < 8)       { src = srcF; mean = stats + 4096; rstd = stats + 5120;
                        out = outp;            M = 1024; Hin = 32; m0 = my * 128; }
    else if (my < 24) { src = srcC; mean = stats + 6144; rstd = stats + 7168;
                        out = outp + 4194304;  M = 2048; Hin = 64; m0 = (my - 8) * 128; }
    else              { src = srcL; mean = stats + 8192; rstd = stats + 9216;
                        out = outp + 12582912; M = 2048; Hin = 64; m0 = (my - 24) * 128; }
    const float* Ab = src + (size_t)b * M * 128;
    const float* mb = mean + b * 128;
    const float* rb = rstd + b * 128;

    f32x4 acc[4][4];
#pragma unroll
    for (int mi = 0; mi < 4; mi++)
#pragma unroll
        for (int ni = 0; ni < 4; ni++) acc[mi][ni] = (f32x4){0.f, 0.f, 0.f, 0.f};

    for (int k0 = 0; k0 < 128; k0 += 32) {
        for (int i = tid; i < 1024; i += TPB) {
            int row = i >> 3, kc = (i & 7) * 4;
            float4 va = *(const float4*)&Ab[(size_t)(m0 + row) * 128 + k0 + kc];
            float4 mn = *(const float4*)&mb[k0 + kc];
            float4 rs = *(const float4*)&rb[k0 + kc];
            ushort4 u;
            u.x = f2bf(fmaxf((va.x - mn.x) * rs.x, 0.f));
            u.y = f2bf(fmaxf((va.y - mn.y) * rs.y, 0.f));
            u.z = f2bf(fmaxf((va.z - mn.z) * rs.z, 0.f));
            u.w = f2bf(fmaxf((va.w - mn.w) * rs.w, 0.f));
            *(ushort4*)&As[row * 40 + kc] = u;
        }
        for (int i = tid; i < 512; i += TPB) {
            int n = i >> 2, kc = (i & 3) * 8;
            *(bf16x8*)&Bs[n * 40 + kc] = *(const bf16x8*)&ctT[(size_t)(n0 + n) * 128 + k0 + kc];
        }
        __syncthreads();
        bf16x8 af[4], bfr[4];
#pragma unroll
        for (int mi = 0; mi < 4; mi++)
            af[mi] = *(bf16x8*)&As[(wm * 64 + mi * 16 + l16) * 40 + lhi * 8];
#pragma unroll
        for (int ni = 0; ni < 4; ni++)
            bfr[ni] = *(bf16x8*)&Bs[(wn * 64 + ni * 16 + l16) * 40 + lhi * 8];
#pragma unroll
        for (int mi = 0; mi < 4; mi++)
#pragma unroll
            for (int ni = 0; ni < 4; ni++)
                acc[mi][ni] = __builtin_amdgcn_mfma_f32_16x16x32_bf16(af[mi], bfr[ni], acc[mi][ni], 0, 0, 0);
        __syncthreads();
    }
    int Ho = 2 * Hin, Wo = 64;
#pragma unroll
    for (int mi = 0; mi < 4; mi++) {
#pragma unroll
        for (int ni = 0; ni < 4; ni++) {
            int col = n0 + wn * 64 + ni * 16 + l16;
            int oc = col >> 2, aa = (col >> 1) & 1, dd = col & 1;
            int p0 = m0 + wm * 64 + mi * 16 + lhi * 4;
            int hin = p0 >> 5, win0 = p0 & 31;
            float s0 = __shfl_xor(acc[mi][ni][0], 1);
            float s1 = __shfl_xor(acc[mi][ni][1], 1);
            float s2 = __shfl_xor(acc[mi][ni][2], 1);
            float s3 = __shfl_xor(acc[mi][ni][3], 1);
            float4 o;
            if (!dd) o = make_float4(acc[mi][ni][0], s0, acc[mi][ni][1], s1);
            else     o = make_float4(s2, acc[mi][ni][2], s3, acc[mi][ni][3]);
            size_t addr = (((size_t)b * 128 + oc) * Ho + 2 * hin + aa) * Wo
                        + 2 * win0 + (dd ? 4 : 0);
            *(float4*)&out[addr] = o;
        }
    }
}

// ---------------------------------------------------------------------------
// bf16 flash attention (swapped-QK^T, exp2, cvt_pk, prefetch, XCD grid,
// setprio).
// ---------------------------------------------------------------------------
__global__ __launch_bounds__(256, 2) void k_attn_bf16(
        const unsigned short* __restrict__ qb, const unsigned short* __restrict__ kb,
        const unsigned short* __restrict__ vt, unsigned short* __restrict__ aout) {
    __shared__ __align__(16) unsigned short smem[24576];
    unsigned short* Ks = smem;
    unsigned short* Vt = smem + 8192;
    unsigned short* Ps = smem + 16384;
    int tid = threadIdx.x;
    int lane = tid & 63, w = tid >> 6;
    int l16 = lane & 15, lhi = lane >> 4;
    int bid = blockIdx.x;
    int xcd = bid & 7, j = bid >> 3;
    int hz = xcd * 8 + (j >> 4);
    int qt = j & 15;
    int h = hz & 3, z = hz >> 2;
    int bh_q = (z & 7) * 4 + h;
    int bh_kv = z * 4 + h;
    unsigned short* Pw = Ps + w * 2048;

    const unsigned short* qg = qb + ((size_t)bh_q * 2048 + qt * 128) * 128;
    bf16x8 qa[2][4];
#pragma unroll
    for (int mt = 0; mt < 2; mt++) {
        int r = w * 32 + mt * 16 + l16;
#pragma unroll
        for (int ks = 0; ks < 4; ks++)
            qa[mt][ks] = *(const bf16x8*)&qg[(size_t)r * 128 + ks * 32 + lhi * 8];
    }

    f32x4 acc[2][8];
#pragma unroll
    for (int mt = 0; mt < 2; mt++)
#pragma unroll
        for (int dt = 0; dt < 8; dt++) acc[mt][dt] = (f32x4){0.f, 0.f, 0.f, 0.f};
    float m_r[2] = {-1e30f, -1e30f};
    float l_r[2] = {0.f, 0.f};

    const unsigned short* kg = kb + (size_t)bh_kv * 131072;
    const unsigned short* vg = vt + (size_t)bh_kv * 131072;

    int krow = tid >> 4, kcol = (tid & 15) * 8;
    int kls = ((tid & 15) ^ (krow & 7)) << 3;
    int vrow = tid >> 3, vcol = (tid & 7) * 8;
    int vls = ((tid & 7) ^ (vrow & 7)) << 3;

#pragma unroll
    for (int jj = 0; jj < 4; jj++) {
        int r = krow + jj * 16;
        *(bf16x8*)&Ks[r * 128 + kls] = *(const bf16x8*)&kg[(size_t)r * 128 + kcol];
        int d = vrow + jj * 32;
        *(bf16x8*)&Vt[d * 64 + vls] = *(const bf16x8*)&vg[(size_t)d * 1024 + vcol];
    }
    __syncthreads();

    for (int c = 0; c < 16; c++) {
        bf16x8 kpre[4], vpre[4];
        if (c < 15) {
            int c0 = (c + 1) * 64;
#pragma unroll
            for (int jj = 0; jj < 4; jj++) {
                kpre[jj] = *(const bf16x8*)&kg[(size_t)(c0 + krow + jj * 16) * 128 + kcol];
                vpre[jj] = *(const bf16x8*)&vg[(size_t)(vrow + jj * 32) * 1024 + c0 + vcol];
            }
        }

        f32x4 s[2][4];
#pragma unroll
        for (int mt = 0; mt < 2; mt++)
#pragma unroll
            for (int kt = 0; kt < 4; kt++) s[mt][kt] = (f32x4){0.f, 0.f, 0.f, 0.f};
        __builtin_amdgcn_s_setprio(1);
#pragma unroll
        for (int kt = 0; kt < 4; kt++) {
            int r = kt * 16 + l16;
#pragma unroll
            for (int ks = 0; ks < 4; ks++) {
                bf16x8 kf = *(bf16x8*)&Ks[r * 128 + (((ks * 4 + lhi) ^ (r & 7)) << 3)];
                s[0][kt] = __builtin_amdgcn_mfma_f32_16x16x32_bf16(kf, qa[0][ks], s[0][kt], 0, 0, 0);
                s[1][kt] = __builtin_amdgcn_mfma_f32_16x16x32_bf16(kf, qa[1][ks], s[1][kt], 0, 0, 0);
            }
        }
        __builtin_amdgcn_s_setprio(0);

        float pm[2];
#pragma unroll
        for (int mt = 0; mt < 2; mt++) {
            float a = s[mt][0][0];
#pragma unroll
            for (int kt = 0; kt < 4; kt++)
#pragma unroll
                for (int rg = 0; rg < 4; rg++) a = fmaxf(a, s[mt][kt][rg]);
            a = fmaxf(a, __shfl_xor(a, 16));
            a = fmaxf(a, __shfl_xor(a, 32));
            pm[mt] = a;
        }
        bool need = (pm[0] > m_r[0] + 8.f) || (pm[1] > m_r[1] + 8.f);
        if (__any(need)) {
#pragma unroll
            for (int mt = 0; mt < 2; mt++) {
                float mn = fmaxf(m_r[mt], pm[mt]);
                float f = __builtin_amdgcn_exp2f(m_r[mt] - mn);
                m_r[mt] = mn;
                l_r[mt] *= f;
#pragma unroll
                for (int rg = 0; rg < 4; rg++) {
                    float ft = __shfl(f, lhi * 4 + rg);
#pragma unroll
                    for (int dt = 0; dt < 8; dt++) acc[mt][dt][rg] *= ft;
                }
            }
        }

#pragma unroll
        for (int mt = 0; mt < 2; mt++) {
            int row = mt * 16 + l16;
            int rsw = row & 7;
            float ls = 0.f;
#pragma unroll
            for (int kt = 0; kt < 4; kt++) {
                float p0 = __builtin_amdgcn_exp2f(s[mt][kt][0] - m_r[mt]);
                float p1 = __builtin_amdgcn_exp2f(s[mt][kt][1] - m_r[mt]);
                float p2 = __builtin_amdgcn_exp2f(s[mt][kt][2] - m_r[mt]);
                float p3 = __builtin_amdgcn_exp2f(s[mt][kt][3] - m_r[mt]);
                ls += (p0 + p1) + (p2 + p3);
                unsigned u01, u23;
                asm("v_cvt_pk_bf16_f32 %0, %1, %2" : "=v"(u01) : "v"(p0), "v"(p1));
                asm("v_cvt_pk_bf16_f32 %0, %1, %2" : "=v"(u23) : "v"(p2), "v"(p3));
                int slot = kt * 2 + (lhi >> 1);
                int base = row * 64 + ((slot ^ rsw) << 3) + (lhi & 1) * 4;
                *(unsigned*)&Pw[base] = u01;
                *(unsigned*)&Pw[base + 2] = u23;
            }
            l_r[mt] += ls;
        }
        asm volatile("s_waitcnt lgkmcnt(0)" ::: "memory");

        bf16x8 pa0[2], pa1[2];
#pragma unroll
        for (int mt = 0; mt < 2; mt++) {
            int row = mt * 16 + l16;
            pa0[mt] = *(bf16x8*)&Pw[row * 64 + ((lhi ^ (row & 7)) << 3)];
            pa1[mt] = *(bf16x8*)&Pw[row * 64 + (((4 + lhi) ^ (row & 7)) << 3)];
        }
        __builtin_amdgcn_s_setprio(1);
#pragma unroll
        for (int dt = 0; dt < 8; dt++) {
            int d = dt * 16 + l16;
            bf16x8 vb0 = *(bf16x8*)&Vt[d * 64 + ((lhi ^ (d & 7)) << 3)];
            bf16x8 vb1 = *(bf16x8*)&Vt[d * 64 + (((4 + lhi) ^ (d & 7)) << 3)];
            acc[0][dt] = __builtin_amdgcn_mfma_f32_16x16x32_bf16(pa0[0], vb0, acc[0][dt], 0, 0, 0);
            acc[0][dt] = __builtin_amdgcn_mfma_f32_16x16x32_bf16(pa1[0], vb1, acc[0][dt], 0, 0, 0);
            acc[1][dt] = __builtin_amdgcn_mfma_f32_16x16x32_bf16(pa0[1], vb0, acc[1][dt], 0, 0, 0);
            acc[1][dt] = __builtin_amdgcn_mfma_f32_16x16x32_bf16(pa1[1], vb1, acc[1][dt], 0, 0, 0);
        }
        __builtin_amdgcn_s_setprio(0);
        __syncthreads();

        if (c < 15) {
#pragma unroll
            for (int jj = 0; jj < 4; jj++) {
                *(bf16x8*)&Ks[(krow + jj * 16) * 128 + kls] = kpre[jj];
                *(bf16x8*)&Vt[(vrow + jj * 32) * 64 + vls] = vpre[jj];
            }
            __syncthreads();
        }
    }

#pragma unroll
    for (int mt = 0; mt < 2; mt++) {
        float lt = l_r[mt];
        lt += __shfl_xor(lt, 16);
        lt += __shfl_xor(lt, 32);
        l_r[mt] = lt;
    }
    size_t obase = (size_t)(z >> 3) * 16384 + (size_t)(z & 7) * 2048;
#pragma unroll
    for (int mt = 0; mt < 2; mt++)
#pragma unroll
        for (int rg = 0; rg < 4; rg++) {
            float linv = 1.f / __shfl(l_r[mt], lhi * 4 + rg);
            int qrow = qt * 128 + w * 32 + mt * 16 + lhi * 4 + rg;
            unsigned short* orow = aout + (obase + qrow) * 512 + h * 128;
#pragma unroll
            for (int dt = 0; dt < 8; dt++)
                orow[dt * 16 + l16] = f2bf(acc[mt][dt][rg] * linv);
        }
}

// ---------------------------------------------------------------------------
// fused_s write + stats partials in one pass. grid (16, 8).
// ---------------------------------------------------------------------------
__global__ void k_fused_stats(const float* __restrict__ zc, const float* __restrict__ zl,
                              float* __restrict__ fs, float* __restrict__ part) {
    int c = blockIdx.x, b = blockIdx.y;
    int tid = threadIdx.x;
    int d = tid & 127, half = tid >> 7;
    size_t base0 = ((size_t)b * 2048 + c * 64) * 128;
    size_t base1 = ((size_t)b * 2048 + 1024 + c * 64) * 128;
    float s = 0.f, s2 = 0.f;
    for (int t = half; t < 64; t += 2) {
        float v = zc[base0 + t * 128 + d] + zc[base1 + t * 128 + d]
                + zl[base0 + t * 128 + d] + zl[base1 + t * 128 + d];
        fs[((size_t)b * 1024 + c * 64 + t) * 128 + d] = v;
        s += v; s2 += v * v;
    }
    __shared__ float ls[256], ls2[256];
    ls[tid] = s; ls2[tid] = s2;
    __syncthreads();
    if (tid < 128) {
        s = ls[tid] + ls[tid + 128];
        s2 = ls2[tid] + ls2[tid + 128];
        float* p = part + ((size_t)(b * 16 + c) * 2) * 128;
        p[d] = s; p[128 + d] = s2;
    }
}

// ---------------------------------------------------------------------------
extern "C" void kernel_launch(void* const* d_in, const int* in_sizes, int n_in,
                              void* d_out, int out_size, void* d_ws, size_t ws_size,
                              hipStream_t stream) {
    const float* cam_feat = (const float*)d_in[0];
    const float* lid_feat = (const float*)d_in[1];
    const float* pos      = (const float*)d_in[2];
    const float* conv_w   = (const float*)d_in[3];
    const float* convT_w  = (const float*)d_in[4];
    const float* lnq_g = (const float*)d_in[5];
    const float* lnq_b = (const float*)d_in[6];
    const float* wq    = (const float*)d_in[7];
    const float* lnk_g = (const float*)d_in[8];
    const float* lnk_b = (const float*)d_in[9];
    const float* wk    = (const float*)d_in[10];
    const float* lnv_g = (const float*)d_in[11];
    const float* lnv_b = (const float*)d_in[12];
    const float* wv    = (const float*)d_in[13];
    const float* proj_w = (const float*)d_in[14];
    const float* proj_b = (const float*)d_in[15];
    const float* pre_g = (const float*)d_in[16];
    const float* pre_b = (const float*)d_in[17];
    const float* mlp_w1 = (const float*)d_in[18];
    const float* mlp_b1 = (const float*)d_in[19];
    const float* mlp_w2 = (const float*)d_in[20];
    const float* mlp_b2 = (const float*)d_in[21];
    const float* post_g = (const float*)d_in[22];
    const float* post_b = (const float*)d_in[23];

    float* ws = (float*)d_ws;
    float* outp = (float*)d_out;

    // persistent buffers (floats)
    float* cam_eT  = ws + 0;               // 1,048,576
    float* lid_eT  = ws + 1048576;         // 1,048,576
    unsigned short* qbf16 = (unsigned short*)(ws + 2097152);   // 4,194,304 f
    float* z_cam   = ws + 6291456;         // 2,097,152
    float* z_lid   = ws + 8388608;         // 2,097,152
    float* fused_s = ws + 10485760;        // 1,048,576
    float* stats   = ws + 11534336;        // 16,384
    unsigned short* wbuf = (unsigned short*)(ws + 11550720);   // 196,608 f
    float* part    = ws + 11747328;        // 131,072
    float* mean_e  = ws + 11878400;        // 16,384
    float* rstd_e  = ws + 11894784;        // 16,384
    float* bvecs   = ws + 11911168;        // 1,536
    unsigned short* xcolT = (unsigned short*)(ws + 11912704);  // 4,194,304 f
    float* pool    = ws + 16107008;        // 16,777,216

    unsigned short* wqT   = wbuf + 0;
    unsigned short* wkT   = wbuf + 65536;
    unsigned short* wvT   = wbuf + 131072;
    unsigned short* projT = wbuf + 196608;
    unsigned short* m1T   = wbuf + 262144;
    unsigned short* m2T   = wbuf + 294912;
    unsigned short* ctT   = wbuf + 327680;

    float* meanA = stats + 0,    *rstdA = stats + 2048;
    float* meanF = stats + 4096, *rstdF = stats + 5120;

    // pool (timeline-overlapped)
    unsigned short* kbf16 = (unsigned short*)(pool + 0);        // 4,194,304 f
    unsigned short* vbfT  = (unsigned short*)(pool + 4194304);  // 4,194,304 f
    unsigned short* abuf  = (unsigned short*)(pool + 8388608);  // 8,388,608 f

    // 1/sqrt(128) * log2(e): attention softmax runs in the exp2 domain
    const float qscale = 0.12751744436f;

    // Weight prep + bias vectors (one launch)
    k_wtrans_all<<<390, TPB, 0, stream>>>(wq, wk, wv, proj_w, mlp_w1, mlp_w2, convT_w,
                                          lnq_g, lnk_g, lnv_g, lnq_b, lnk_b, lnv_b,
                                          wqT, wkT, wvT, projT, m1T, m2T, ctT, bvecs);

    // Stage A: stats + conv encoders (conv epilogue emits per-token LN stats)
    k_stats_cm<<<2048, TPB, 0, stream>>>(cam_feat, lid_feat, pos, meanA, rstdA);
    k_prep<<<dim3(32, 16), TPB, 0, stream>>>(cam_feat, lid_feat, pos, meanA, rstdA, xcolT);
    k_conv_gemm<<<dim3(16, 1, 16), TPB, 0, stream>>>(conv_w, xcolT, cam_eT, lid_eT,
                                                     mean_e, rstd_e);

    // Q/K/V; attention; fused tail (proj+preLN+mlp1+mlp2+postLN+stats)
    k_qkv_gemm<<<dim3(12, 128), TPB, 0, stream>>>(
        cam_eT, lid_eT, mean_e, rstd_e, wqT, wkT, wvT, qbf16, kbf16, vbfT,
        bvecs, qscale);
    k_attn_bf16<<<1024, TPB, 0, stream>>>(qbf16, kbf16, vbfT, abuf);
    k_tail_fused<<<512, TPB, 0, stream>>>(
        abuf, projT, m1T, m2T, cam_eT, lid_eT, proj_b, pre_g, pre_b,
        mlp_b1, mlp_b2, post_g, post_b, z_cam, z_lid, part);

    // Outputs
    k_stats_red2<<<16, 128, 0, stream>>>(part, stats + 6144, stats + 7168,
                                         stats + 8192, stats + 9216);
    k_fused_stats<<<dim3(16, 8), TPB, 0, stream>>>(z_cam, z_lid, fused_s, part + 65536);
    k_stats_red<<<8, 128, 0, stream>>>(part + 65536, meanF, rstdF, 16, 1024);
    k_convt_gemm<<<dim3(4, 40, 8), TPB, 0, stream>>>(fused_s, z_cam, z_lid, stats,
                                                     ctT, outp);
}

// Round 14
// 267.293 us; speedup vs baseline: 19.2560x; 1.0016x over previous
//
#include <hip/hip_runtime.h>
#include <math.h>

#define TPB 256

typedef __attribute__((ext_vector_type(8))) short bf16x8;
typedef __attribute__((ext_vector_type(4))) float f32x4;

__device__ __forceinline__ float gelu_exact(float x) {
    return 0.5f * x * (1.0f + erff(x * 0.70710678118654752f));
}

__device__ __forceinline__ unsigned short f2bf(float x) {
    unsigned u = __float_as_uint(x);
    return (unsigned short)((u + 0x7fffu + ((u >> 16) & 1u)) >> 16);
}

// ---------------------------------------------------------------------------
// Stage-A instance-norm stats (x + pos broadcast), 2048 channels.
// ---------------------------------------------------------------------------
__global__ void k_stats_cm(const float* __restrict__ x0, const float* __restrict__ x1,
                           const float* __restrict__ pos, float* __restrict__ mean,
                           float* __restrict__ rstd) {
    int gc = blockIdx.x;
    const float* src = ((gc < 1024) ? x0 : x1) + (size_t)(gc & 1023) * 4096;
    const float* posr = pos + (size_t)(gc & 127) * 4096;
    float s = 0.f, s2 = 0.f;
    for (int p = threadIdx.x; p < 4096; p += TPB) {
        float v = src[p] + posr[p];
        s += v; s2 += v * v;
    }
#pragma unroll
    for (int m = 32; m; m >>= 1) { s += __shfl_xor(s, m); s2 += __shfl_xor(s2, m); }
    __shared__ float ls[4], ls2[4];
    int w = threadIdx.x >> 6;
    if ((threadIdx.x & 63) == 0) { ls[w] = s; ls2[w] = s2; }
    __syncthreads();
    if (threadIdx.x == 0) {
        s = ls[0] + ls[1] + ls[2] + ls[3];
        s2 = ls2[0] + ls2[1] + ls2[2] + ls2[3];
        float mu = s / 4096.f;
        float var = s2 / 4096.f - mu * mu;
        mean[gc] = mu;
        rstd[gc] = rsqrtf(var + 1e-5f);
    }
}

// ---------------------------------------------------------------------------
// Token-major stats reduces.
// ---------------------------------------------------------------------------
__global__ void k_stats_red(const float* __restrict__ part, float* __restrict__ mean,
                            float* __restrict__ rstd, int nc, int T) {
    int b = blockIdx.x, d = threadIdx.x;
    float s = 0.f, s2 = 0.f;
    for (int c = 0; c < nc; c++) {
        const float* p = part + ((size_t)(b * nc + c) * 2) * 128;
        s += p[d]; s2 += p[128 + d];
    }
    float mu = s / (float)T;
    float var = s2 / (float)T - mu * mu;
    mean[b * 128 + d] = mu;
    rstd[b * 128 + d] = rsqrtf(var + 1e-5f);
}

__global__ void k_stats_red2(const float* __restrict__ part,
                             float* __restrict__ meanC, float* __restrict__ rstdC,
                             float* __restrict__ meanL, float* __restrict__ rstdL) {
    int idx = blockIdx.x, d = threadIdx.x;
    int sel = idx >> 3, b = idx & 7;
    float s = 0.f, s2 = 0.f;
    for (int c = 0; c < 32; c++) {
        const float* p = part + ((size_t)((sel * 8 + b) * 32 + c) * 2) * 128;
        s += p[d]; s2 += p[128 + d];
    }
    float mu = s / 2048.f;
    float var = s2 / 2048.f - mu * mu;
    float* mean = sel ? meanL : meanC;
    float* rstd = sel ? rstdL : rstdC;
    mean[b * 128 + d] = mu;
    rstd[b * 128 + d] = rsqrtf(var + 1e-5f);
}

// ---------------------------------------------------------------------------
// Conv prep (cam+lid merged): normalize+ReLU+im2col -> bf16 xcolT[bb][p][512].
// ---------------------------------------------------------------------------
__global__ void k_prep(const float* __restrict__ cam, const float* __restrict__ lid,
                       const float* __restrict__ pos, const float* __restrict__ mean,
                       const float* __restrict__ rstd, unsigned short* __restrict__ xcolT) {
    __shared__ unsigned short T[32 * 520];
    int h = blockIdx.x, bb = blockIdx.y;
    int b = bb & 7, so = (bb < 8) ? 0 : 1024;
    const float* x = (bb < 8) ? cam : lid;
    int tid = threadIdx.x;
    for (int i = tid; i < 4096; i += TPB) {
        int c = i >> 5, w = i & 31;
        int ch = b * 128 + c;
        const float* xr = x + (size_t)ch * 4096 + (2 * h) * 64 + 2 * w;
        const float* pr = pos + (size_t)c * 4096 + (2 * h) * 64 + 2 * w;
        float mu = mean[so + ch], rs = rstd[so + ch];
        float2 x0 = *(const float2*)xr;
        float2 x1 = *(const float2*)(xr + 64);
        float2 p0 = *(const float2*)pr;
        float2 p1 = *(const float2*)(pr + 64);
        ushort4 u;
        u.x = f2bf(fmaxf((x0.x + p0.x - mu) * rs, 0.f));
        u.y = f2bf(fmaxf((x0.y + p0.y - mu) * rs, 0.f));
        u.z = f2bf(fmaxf((x1.x + p1.x - mu) * rs, 0.f));
        u.w = f2bf(fmaxf((x1.y + p1.y - mu) * rs, 0.f));
        *(ushort4*)&T[w * 520 + c * 4] = u;
    }
    __syncthreads();
    unsigned short* dst = xcolT + ((size_t)bb * 1024 + h * 32) * 512;
    for (int i = tid; i < 2048; i += TPB) {
        int w = i >> 6, kk = (i & 63) * 8;
        *(bf16x8*)&dst[(size_t)w * 512 + kk] = *(bf16x8*)&T[w * 520 + kk];
    }
}

// ---------------------------------------------------------------------------
// Conv as batched MFMA GEMM (cam+lid merged) + per-token LN stats epilogue.
// grid (16, 1, 16).
// ---------------------------------------------------------------------------
__global__ __launch_bounds__(256, 2) void k_conv_gemm(
        const float* __restrict__ W, const unsigned short* __restrict__ xcolT,
        float* __restrict__ camT, float* __restrict__ lidT,
        float* __restrict__ mean_e, float* __restrict__ rstd_e) {
    __shared__ __align__(16) unsigned short As[128 * 40];
    __shared__ __align__(16) unsigned short Bs[64 * 40];
    __shared__ float red[2048];
    int tid = threadIdx.x, lane = tid & 63, w = tid >> 6;
    int l16 = lane & 15, lhi = lane >> 4;
    int n0 = blockIdx.x * 64, bb = blockIdx.z;
    const unsigned short* BT = xcolT + (size_t)bb * 524288;
    float* eT = ((bb < 8) ? camT : lidT) + (size_t)(bb & 7) * 131072;

    f32x4 acc[2][4];
#pragma unroll
    for (int mi = 0; mi < 2; mi++)
#pragma unroll
        for (int ni = 0; ni < 4; ni++) acc[mi][ni] = (f32x4){0.f, 0.f, 0.f, 0.f};

    for (int k0 = 0; k0 < 512; k0 += 32) {
        for (int i = tid; i < 1024; i += TPB) {
            int row = i >> 3, kc = (i & 7) * 4;
            float4 va = *(const float4*)&W[(size_t)row * 512 + k0 + kc];
            ushort4 u;
            u.x = f2bf(va.x); u.y = f2bf(va.y); u.z = f2bf(va.z); u.w = f2bf(va.w);
            *(ushort4*)&As[row * 40 + kc] = u;
        }
        for (int i = tid; i < 256; i += TPB) {
            int n = i >> 2, kc = (i & 3) * 8;
            *(bf16x8*)&Bs[n * 40 + kc] = *(const bf16x8*)&BT[(size_t)(n0 + n) * 512 + k0 + kc];
        }
        __syncthreads();
        bf16x8 af[2], bfr[4];
#pragma unroll
        for (int mi = 0; mi < 2; mi++)
            af[mi] = *(bf16x8*)&As[(w * 32 + mi * 16 + l16) * 40 + lhi * 8];
#pragma unroll
        for (int ni = 0; ni < 4; ni++)
            bfr[ni] = *(bf16x8*)&Bs[(ni * 16 + l16) * 40 + lhi * 8];
#pragma unroll
        for (int mi = 0; mi < 2; mi++)
#pragma unroll
            for (int ni = 0; ni < 4; ni++)
                acc[mi][ni] = __builtin_amdgcn_mfma_f32_16x16x32_bf16(af[mi], bfr[ni], acc[mi][ni], 0, 0, 0);
        __syncthreads();
    }
#pragma unroll
    for (int mi = 0; mi < 2; mi++)
#pragma unroll
        for (int ni = 0; ni < 4; ni++) {
            int col = n0 + ni * 16 + l16;
            int rowb = w * 32 + mi * 16 + lhi * 4;
            *(float4*)&eT[(size_t)col * 128 + rowb] = *(float4*)&acc[mi][ni];
        }
#pragma unroll
    for (int ni = 0; ni < 4; ni++) {
        float s = 0.f, s2 = 0.f;
#pragma unroll
        for (int mi = 0; mi < 2; mi++)
#pragma unroll
            for (int rg = 0; rg < 4; rg++) {
                float v = acc[mi][ni][rg];
                s += v; s2 += v * v;
            }
        int idx = (ni * 16 + l16) * 16 + w * 4 + lhi;
        red[idx] = s;
        red[1024 + idx] = s2;
    }
    __syncthreads();
    if (tid < 64) {
        int ni = tid >> 4, c16 = tid & 15;
        float s = 0.f, s2 = 0.f;
#pragma unroll
        for (int j = 0; j < 16; j++) {
            s += red[(ni * 16 + c16) * 16 + j];
            s2 += red[1024 + (ni * 16 + c16) * 16 + j];
        }
        int col = n0 + ni * 16 + c16;
        int tok = bb * 1024 + col;
        float mu = s * (1.f / 128.f);
        float var = s2 * (1.f / 128.f) - mu * mu;
        mean_e[tok] = mu;
        rstd_e[tok] = rsqrtf(var + 1e-5f);
    }
}

// ---------------------------------------------------------------------------
// Weight transposes (bid<384, gamma-prescaled Q/K/V) + beta@W bias vectors
// (bid 384..389) in ONE launch. grid 390.
// ---------------------------------------------------------------------------
__global__ void k_wtrans_all(
        const float* __restrict__ wq, const float* __restrict__ wk,
        const float* __restrict__ wv, const float* __restrict__ proj,
        const float* __restrict__ m1, const float* __restrict__ m2,
        const float* __restrict__ ct,
        const float* __restrict__ gq, const float* __restrict__ gk,
        const float* __restrict__ gv,
        const float* __restrict__ bq_in, const float* __restrict__ bk_in,
        const float* __restrict__ bv_in,
        unsigned short* wqT, unsigned short* wkT, unsigned short* wvT,
        unsigned short* projT, unsigned short* m1T, unsigned short* m2T,
        unsigned short* ctT, float* __restrict__ bout) {
    __shared__ float t[32][33];
    int bid = blockIdx.x;
    int tid = threadIdx.x;
    if (bid >= 384) {
        int i = bid - 384;
        int which = i >> 1, half = i & 1;
        const float* W = (which == 0) ? wq : (which == 1) ? wk : wv;
        const float* bb = (which == 0) ? bq_in : (which == 1) ? bk_in : bv_in;
        int n = half * 256 + tid;
        float s = 0.f;
        for (int k = 0; k < 128; k++) s += bb[k] * W[(size_t)k * 512 + n];
        bout[which * 512 + n] = s;
        return;
    }
    const float* W; unsigned short* WT; const float* sc = nullptr; int K, N, ti;
    if (bid < 64)       { W = wq;   WT = wqT;   sc = gq; K = 128; N = 512; ti = bid; }
    else if (bid < 128) { W = wk;   WT = wkT;   sc = gk; K = 128; N = 512; ti = bid - 64; }
    else if (bid < 192) { W = wv;   WT = wvT;   sc = gv; K = 128; N = 512; ti = bid - 128; }
    else if (bid < 256) { W = proj; WT = projT; K = 512; N = 128; ti = bid - 192; }
    else if (bid < 288) { W = m1;   WT = m1T;   K = 128; N = 256; ti = bid - 256; }
    else if (bid < 320) { W = m2;   WT = m2T;   K = 256; N = 128; ti = bid - 288; }
    else                { W = ct;   WT = ctT;   K = 128; N = 512; ti = bid - 320; }
    int tx = N >> 5;
    int n0 = (ti % tx) * 32, k0 = (ti / tx) * 32;
    for (int i = tid; i < 1024; i += TPB) {
        int r = i >> 5, c = i & 31;
        float v = W[(size_t)(k0 + r) * N + n0 + c];
        if (sc) v *= sc[k0 + r];
        t[r][c] = v;
    }
    __syncthreads();
    for (int i = tid; i < 1024; i += TPB) {
        int r = i >> 5, c = i & 31;
        WT[(size_t)(n0 + r) * K + k0 + c] = f2bf(t[c][r]);
    }
}

// ---------------------------------------------------------------------------
// Merged Q/K/V projection GEMM with fused LN on A. grid (12, 128).
// ---------------------------------------------------------------------------
__global__ __launch_bounds__(256, 2) void k_qkv_gemm(
        const float* __restrict__ camT, const float* __restrict__ lidT,
        const float* __restrict__ me, const float* __restrict__ re,
        const unsigned short* __restrict__ wqT, const unsigned short* __restrict__ wkT,
        const unsigned short* __restrict__ wvT,
        unsigned short* __restrict__ qout, unsigned short* __restrict__ kout,
        unsigned short* __restrict__ vout,
        const float* __restrict__ bvecs, float qscale) {
    __shared__ __align__(16) unsigned short As[128 * 40];
    __shared__ __align__(16) unsigned short Bs[128 * 40];
    int tid = threadIdx.x, lane = tid & 63, w = tid >> 6;
    int l16 = lane & 15, lhi = lane >> 4;
    int wm = w >> 1, wn = w & 1;
    int which = blockIdx.x >> 2;
    int n0 = (blockIdx.x & 3) * 128;
    int m0 = blockIdx.y * 128;
    const unsigned short* BT = (which == 0) ? wqT : (which == 1) ? wkT : wvT;
    const float* bias = bvecs + which * 512;

    f32x4 acc[4][4];
#pragma unroll
    for (int mi = 0; mi < 4; mi++)
#pragma unroll
        for (int ni = 0; ni < 4; ni++) acc[mi][ni] = (f32x4){0.f, 0.f, 0.f, 0.f};

    for (int k0 = 0; k0 < 128; k0 += 32) {
        for (int i = tid; i < 1024; i += TPB) {
            int row = i >> 3, kc = (i & 7) * 4;
            int r = m0 + row;
            const float* srow;
            int tok;
            if (which == 0) {
                int b = r >> 11, t = r & 2047;
                bool cam = t < 1024;
                tok = (cam ? b : 8 + b) * 1024 + (t & 1023);
                srow = (cam ? camT : lidT) + (size_t)(b * 1024 + (t & 1023)) * 128;
            } else {
                tok = r;
                srow = ((r < 8192) ? camT : lidT) + (size_t)(r & 8191) * 128;
            }
            float mu = me[tok], rs = re[tok];
            float4 va = *(const float4*)&srow[k0 + kc];
            ushort4 u;
            u.x = f2bf((va.x - mu) * rs); u.y = f2bf((va.y - mu) * rs);
            u.z = f2bf((va.z - mu) * rs); u.w = f2bf((va.w - mu) * rs);
            *(ushort4*)&As[row * 40 + kc] = u;
        }
        for (int i = tid; i < 512; i += TPB) {
            int n = i >> 2, kc = (i & 3) * 8;
            *(bf16x8*)&Bs[n * 40 + kc] = *(const bf16x8*)&BT[(size_t)(n0 + n) * 128 + k0 + kc];
        }
        __syncthreads();
        bf16x8 af[4], bfr[4];
#pragma unroll
        for (int mi = 0; mi < 4; mi++)
            af[mi] = *(bf16x8*)&As[(wm * 64 + mi * 16 + l16) * 40 + lhi * 8];
#pragma unroll
        for (int ni = 0; ni < 4; ni++)
            bfr[ni] = *(bf16x8*)&Bs[(wn * 64 + ni * 16 + l16) * 40 + lhi * 8];
#pragma unroll
        for (int mi = 0; mi < 4; mi++)
#pragma unroll
            for (int ni = 0; ni < 4; ni++)
                acc[mi][ni] = __builtin_amdgcn_mfma_f32_16x16x32_bf16(af[mi], bfr[ni], acc[mi][ni], 0, 0, 0);
        __syncthreads();
    }
#pragma unroll
    for (int mi = 0; mi < 4; mi++) {
#pragma unroll
        for (int ni = 0; ni < 4; ni++) {
            int col = n0 + wn * 64 + ni * 16 + l16;
            float bc = bias[col];
            if (which == 2) {
                int row0 = m0 + wm * 64 + mi * 16 + lhi * 4;
                int bb = row0 >> 10, t0 = row0 & 1023;
                ushort4 u;
                u.x = f2bf(acc[mi][ni][0] + bc); u.y = f2bf(acc[mi][ni][1] + bc);
                u.z = f2bf(acc[mi][ni][2] + bc); u.w = f2bf(acc[mi][ni][3] + bc);
                *(ushort4*)&vout[(((size_t)(bb * 4 + (col >> 7))) * 128 + (col & 127)) * 1024 + t0] = u;
            } else {
                int sT = (which == 0) ? 11 : 10;
                float sc = (which == 0) ? qscale : 1.f;
                unsigned short* C16 = (which == 0) ? qout : kout;
#pragma unroll
                for (int rg = 0; rg < 4; rg++) {
                    int row = m0 + wm * 64 + mi * 16 + lhi * 4 + rg;
                    int bb = row >> sT, t = row & ((1 << sT) - 1);
                    size_t oa = ((((size_t)bb * 4 + (col >> 7)) << sT) + t) * 128 + (col & 127);
                    C16[oa] = f2bf((acc[mi][ni][rg] + bc) * sc);
                }
            }
        }
    }
}

// ---------------------------------------------------------------------------
// FUSED TAIL (round 13, unchanged): proj+preLN+mlp1+mlp2+postLN+stats.
// ---------------------------------------------------------------------------
__global__ __launch_bounds__(256, 2) void k_tail_fused(
        const unsigned short* __restrict__ abuf, const unsigned short* __restrict__ projT,
        const unsigned short* __restrict__ m1T, const unsigned short* __restrict__ m2T,
        const float* __restrict__ camT, const float* __restrict__ lidT,
        const float* __restrict__ proj_b,
        const float* __restrict__ pre_g, const float* __restrict__ pre_b,
        const float* __restrict__ mlp_b1, const float* __restrict__ mlp_b2,
        const float* __restrict__ post_g, const float* __restrict__ post_b,
        float* __restrict__ z_cam, float* __restrict__ z_lid,
        float* __restrict__ part) {
    __shared__ __align__(16) unsigned short shm[21504];  // 43 KB
    int tid = threadIdx.x, lane = tid & 63, w = tid >> 6;
    int l16 = lane & 15, lhi = lane >> 4;
    int m0 = blockIdx.x * 64;
    int tok = w * 16 + l16;
    int grow = m0 + tok;
    int tsw = tok & 7;

    // ---- Phase 1: proj GEMM (K=512), swapped: D[col n][tok] ----
    unsigned short* Ts = shm;          // [64][40]
    unsigned short* Ws = shm + 2560;   // [128][40]
    f32x4 z2[8];
#pragma unroll
    for (int ni = 0; ni < 8; ni++) z2[ni] = (f32x4){0.f, 0.f, 0.f, 0.f};
    for (int k0 = 0; k0 < 512; k0 += 32) {
        for (int i = tid; i < 256; i += TPB) {
            int row = i >> 2, kc = (i & 3) * 8;
            *(bf16x8*)&Ts[row * 40 + kc] =
                *(const bf16x8*)&abuf[(size_t)(m0 + row) * 512 + k0 + kc];
        }
        for (int i = tid; i < 512; i += TPB) {
            int row = i >> 2, kc = (i & 3) * 8;
            *(bf16x8*)&Ws[row * 40 + kc] =
                *(const bf16x8*)&projT[(size_t)row * 512 + k0 + kc];
        }
        __syncthreads();
        bf16x8 bfr = *(bf16x8*)&Ts[tok * 40 + lhi * 8];
#pragma unroll
        for (int ni = 0; ni < 8; ni++) {
            bf16x8 af = *(bf16x8*)&Ws[(ni * 16 + l16) * 40 + lhi * 8];
            z2[ni] = __builtin_amdgcn_mfma_f32_16x16x32_bf16(af, bfr, z2[ni], 0, 0, 0);
        }
        __syncthreads();
    }
    // epilogue 1: + proj_b + skip (width-concat [camT|lidT])
    {
        int rr = grow & 16383;
        int b = rr >> 11, ss = rr & 2047;
        int Hh = ss >> 6, Ww = ss & 63;
        const float* sp = ((Ww < 32) ? camT : lidT)
                        + ((size_t)(b * 1024 + Hh * 32 + (Ww & 31))) * 128;
#pragma unroll
        for (int ni = 0; ni < 8; ni++) {
            int c0 = ni * 16 + lhi * 4;
            float4 pb = *(const float4*)&proj_b[c0];
            float4 sk = *(const float4*)&sp[c0];
            z2[ni][0] += pb.x + sk.x; z2[ni][1] += pb.y + sk.y;
            z2[ni][2] += pb.z + sk.z; z2[ni][3] += pb.w + sk.w;
        }
    }
    // preLN (in-register): z2 <- LN(z2)  [the LN'd value IS the MLP residual]
    unsigned short* z2ln = shm;  // [64][128] swizzled (overwrites Ts/Ws)
    {
        float s = 0.f, s2 = 0.f;
#pragma unroll
        for (int ni = 0; ni < 8; ni++)
#pragma unroll
            for (int rg = 0; rg < 4; rg++) { float v = z2[ni][rg]; s += v; s2 += v * v; }
        s += __shfl_xor(s, 16); s2 += __shfl_xor(s2, 16);
        s += __shfl_xor(s, 32); s2 += __shfl_xor(s2, 32);
        float mu = s * (1.f / 128.f);
        float var = s2 * (1.f / 128.f) - mu * mu;
        float rs = rsqrtf(var + 1e-5f);
#pragma unroll
        for (int ni = 0; ni < 8; ni++) {
            int c0 = ni * 16 + lhi * 4;
            float4 gg = *(const float4*)&pre_g[c0];
            float4 bb = *(const float4*)&pre_b[c0];
            z2[ni][0] = (z2[ni][0] - mu) * rs * gg.x + bb.x;
            z2[ni][1] = (z2[ni][1] - mu) * rs * gg.y + bb.y;
            z2[ni][2] = (z2[ni][2] - mu) * rs * gg.z + bb.z;
            z2[ni][3] = (z2[ni][3] - mu) * rs * gg.w + bb.w;
            unsigned u01, u23;
            asm("v_cvt_pk_bf16_f32 %0, %1, %2" : "=v"(u01) : "v"(z2[ni][0]), "v"(z2[ni][1]));
            asm("v_cvt_pk_bf16_f32 %0, %1, %2" : "=v"(u23) : "v"(z2[ni][2]), "v"(z2[ni][3]));
            int slot = ni * 2 + (lhi >> 1);
            int base = tok * 128 + ((slot ^ tsw) << 3) + (lhi & 1) * 4;
            *(unsigned*)&z2ln[base] = u01;
            *(unsigned*)&z2ln[base + 2] = u23;
        }
    }

    // ---- Phase 2: mlp1 (K=128, N=256), swapped ----
    unsigned short* As1 = shm + 8192;  // [256][40]
    f32x4 a1[16];
#pragma unroll
    for (int ni = 0; ni < 16; ni++) a1[ni] = (f32x4){0.f, 0.f, 0.f, 0.f};
    for (int ks = 0; ks < 4; ks++) {
        int k0 = ks * 32;
        for (int i = tid; i < 1024; i += TPB) {
            int row = i >> 2, kc = (i & 3) * 8;
            *(bf16x8*)&As1[row * 40 + kc] =
                *(const bf16x8*)&m1T[(size_t)row * 128 + k0 + kc];
        }
        __syncthreads();
        bf16x8 bfr = *(bf16x8*)&z2ln[tok * 128 + (((ks * 4 + lhi) ^ tsw) << 3)];
#pragma unroll
        for (int ni = 0; ni < 16; ni++) {
            bf16x8 af = *(bf16x8*)&As1[(ni * 16 + l16) * 40 + lhi * 8];
            a1[ni] = __builtin_amdgcn_mfma_f32_16x16x32_bf16(af, bfr, a1[ni], 0, 0, 0);
        }
        __syncthreads();
    }
    // GELU -> h1 bf16 to LDS
    unsigned short* Hs = shm;  // [64][256] swizzled (overwrites z2ln/As1)
#pragma unroll
    for (int ni = 0; ni < 16; ni++) {
        int c0 = ni * 16 + lhi * 4;
        float4 bb = *(const float4*)&mlp_b1[c0];
        float h0 = gelu_exact(a1[ni][0] + bb.x);
        float h1v = gelu_exact(a1[ni][1] + bb.y);
        float h2 = gelu_exact(a1[ni][2] + bb.z);
        float h3 = gelu_exact(a1[ni][3] + bb.w);
        unsigned u01, u23;
        asm("v_cvt_pk_bf16_f32 %0, %1, %2" : "=v"(u01) : "v"(h0), "v"(h1v));
        asm("v_cvt_pk_bf16_f32 %0, %1, %2" : "=v"(u23) : "v"(h2), "v"(h3));
        int slot = ni * 2 + (lhi >> 1);
        int base = tok * 256 + ((slot ^ tsw) << 3) + (lhi & 1) * 4;
        *(unsigned*)&Hs[base] = u01;
        *(unsigned*)&Hs[base + 2] = u23;
    }

    // ---- Phase 3: mlp2 (K=256, N=128), swapped ----
    unsigned short* As2 = shm + 16384;  // [128][40]
    f32x4 a2[8];
#pragma unroll
    for (int ni = 0; ni < 8; ni++) a2[ni] = (f32x4){0.f, 0.f, 0.f, 0.f};
    for (int ks = 0; ks < 8; ks++) {
        int k0 = ks * 32;
        for (int i = tid; i < 512; i += TPB) {
            int row = i >> 2, kc = (i & 3) * 8;
            *(bf16x8*)&As2[row * 40 + kc] =
                *(const bf16x8*)&m2T[(size_t)row * 256 + k0 + kc];
        }
        __syncthreads();
        bf16x8 bfr = *(bf16x8*)&Hs[tok * 256 + (((ks * 4 + lhi) ^ tsw) << 3)];
#pragma unroll
        for (int ni = 0; ni < 8; ni++) {
            bf16x8 af = *(bf16x8*)&As2[(ni * 16 + l16) * 40 + lhi * 8];
            a2[ni] = __builtin_amdgcn_mfma_f32_16x16x32_bf16(af, bfr, a2[ni], 0, 0, 0);
        }
        __syncthreads();
    }
    // epilogue 3: + mlp_b2 + LN'd-z2 residual -> postLN -> store + stats
    float* O = (float*)shm;  // [64][132] fp32 (overwrites Hs/As2)
    {
#pragma unroll
        for (int ni = 0; ni < 8; ni++) {
            int c0 = ni * 16 + lhi * 4;
            float4 bb = *(const float4*)&mlp_b2[c0];
            a2[ni][0] += bb.x + z2[ni][0];
            a2[ni][1] += bb.y + z2[ni][1];
            a2[ni][2] += bb.z + z2[ni][2];
            a2[ni][3] += bb.w + z2[ni][3];
        }
        float s = 0.f, s2 = 0.f;
#pragma unroll
        for (int ni = 0; ni < 8; ni++)
#pragma unroll
            for (int rg = 0; rg < 4; rg++) { float v = a2[ni][rg]; s += v; s2 += v * v; }
        s += __shfl_xor(s, 16); s2 += __shfl_xor(s2, 16);
        s += __shfl_xor(s, 32); s2 += __shfl_xor(s2, 32);
        float mu = s * (1.f / 128.f);
        float var = s2 * (1.f / 128.f) - mu * mu;
        float rs = rsqrtf(var + 1e-5f);
        float* Cp = (grow < 16384) ? z_cam : z_lid;
        size_t ro = (size_t)(grow & 16383) * 128;
#pragma unroll
        for (int ni = 0; ni < 8; ni++) {
            int c0 = ni * 16 + lhi * 4;
            float4 gg = *(const float4*)&post_g[c0];
            float4 bb = *(const float4*)&post_b[c0];
            float4 o;
            o.x = (a2[ni][0] - mu) * rs * gg.x + bb.x;
            o.y = (a2[ni][1] - mu) * rs * gg.y + bb.y;
            o.z = (a2[ni][2] - mu) * rs * gg.z + bb.z;
            o.w = (a2[ni][3] - mu) * rs * gg.w + bb.w;
            *(float4*)&Cp[ro + c0] = o;
            *(float4*)&O[tok * 132 + c0] = o;
        }
    }
    __syncthreads();
    if (tid < 128) {
        int col = tid;
        float s = 0.f, s2 = 0.f;
        for (int t = 0; t < 64; t++) {
            float v = O[t * 132 + col];
            s += v; s2 += v * v;
        }
        int sel = (m0 >= 16384) ? 1 : 0;
        int rrg = m0 & 16383;
        int b = rrg >> 11, c = (rrg >> 6) & 31;
        float* p = part + ((size_t)((sel * 8 + b) * 32 + c) * 2) * 128;
        p[col] = s; p[128 + col] = s2;
    }
}

// ---------------------------------------------------------------------------
// ConvTranspose, ALL THREE outputs in one launch. grid (4, 40, 8).
// ---------------------------------------------------------------------------
__global__ __launch_bounds__(256, 2) void k_convt_gemm(
        const float* __restrict__ srcF, const float* __restrict__ srcC,
        const float* __restrict__ srcL, const float* __restrict__ stats,
        const unsigned short* __restrict__ ctT, float* __restrict__ outp) {
    __shared__ __align__(16) unsigned short As[128 * 40];
    __shared__ __align__(16) unsigned short Bs[128 * 40];
    int tid = threadIdx.x, lane = tid & 63, w = tid >> 6;
    int l16 = lane & 15, lhi = lane >> 4;
    int wm = w >> 1, wn = w & 1;
    int my = blockIdx.y, n0 = blockIdx.x * 128, b = blockIdx.z;
    const float* src; const float* mean; const float* rstd; float* out;
    int M, Hin, m0;
    if (my < 8)       { src = srcF; mean = stats + 4096; rstd = stats + 5120;
                        out = outp;            M = 1024; Hin = 32; m0 = my * 128; }
    else if (my < 24) { src = srcC; mean = stats + 6144; rstd = stats + 7168;
                        out = outp + 4194304;  M = 2048; Hin = 64; m0 = (my - 8) * 128; }
    else              { src = srcL; mean = stats + 8192; rstd = stats + 9216;
                        out = outp + 12582912; M = 2048; Hin = 64; m0 = (my - 24) * 128; }
    const float* Ab = src + (size_t)b * M * 128;
    const float* mb = mean + b * 128;
    const float* rb = rstd + b * 128;

    f32x4 acc[4][4];
#pragma unroll
    for (int mi = 0; mi < 4; mi++)
#pragma unroll
        for (int ni = 0; ni < 4; ni++) acc[mi][ni] = (f32x4){0.f, 0.f, 0.f, 0.f};

    for (int k0 = 0; k0 < 128; k0 += 32) {
        for (int i = tid; i < 1024; i += TPB) {
            int row = i >> 3, kc = (i & 7) * 4;
            float4 va = *(const float4*)&Ab[(size_t)(m0 + row) * 128 + k0 + kc];
            float4 mn = *(const float4*)&mb[k0 + kc];
            float4 rs = *(const float4*)&rb[k0 + kc];
            ushort4 u;
            u.x = f2bf(fmaxf((va.x - mn.x) * rs.x, 0.f));
            u.y = f2bf(fmaxf((va.y - mn.y) * rs.y, 0.f));
            u.z = f2bf(fmaxf((va.z - mn.z) * rs.z, 0.f));
            u.w = f2bf(fmaxf((va.w - mn.w) * rs.w, 0.f));
            *(ushort4*)&As[row * 40 + kc] = u;
        }
        for (int i = tid; i < 512; i += TPB) {
            int n = i >> 2, kc = (i & 3) * 8;
            *(bf16x8*)&Bs[n * 40 + kc] = *(const bf16x8*)&ctT[(size_t)(n0 + n) * 128 + k0 + kc];
        }
        __syncthreads();
        bf16x8 af[4], bfr[4];
#pragma unroll
        for (int mi = 0; mi < 4; mi++)
            af[mi] = *(bf16x8*)&As[(wm * 64 + mi * 16 + l16) * 40 + lhi * 8];
#pragma unroll
        for (int ni = 0; ni < 4; ni++)
            bfr[ni] = *(bf16x8*)&Bs[(wn * 64 + ni * 16 + l16) * 40 + lhi * 8];
#pragma unroll
        for (int mi = 0; mi < 4; mi++)
#pragma unroll
            for (int ni = 0; ni < 4; ni++)
                acc[mi][ni] = __builtin_amdgcn_mfma_f32_16x16x32_bf16(af[mi], bfr[ni], acc[mi][ni], 0, 0, 0);
        __syncthreads();
    }
    int Ho = 2 * Hin, Wo = 64;
#pragma unroll
    for (int mi = 0; mi < 4; mi++) {
#pragma unroll
        for (int ni = 0; ni < 4; ni++) {
            int col = n0 + wn * 64 + ni * 16 + l16;
            int oc = col >> 2, aa = (col >> 1) & 1, dd = col & 1;
            int p0 = m0 + wm * 64 + mi * 16 + lhi * 4;
            int hin = p0 >> 5, win0 = p0 & 31;
            float s0 = __shfl_xor(acc[mi][ni][0], 1);
            float s1 = __shfl_xor(acc[mi][ni][1], 1);
            float s2 = __shfl_xor(acc[mi][ni][2], 1);
            float s3 = __shfl_xor(acc[mi][ni][3], 1);
            float4 o;
            if (!dd) o = make_float4(acc[mi][ni][0], s0, acc[mi][ni][1], s1);
            else     o = make_float4(s2, acc[mi][ni][2], s3, acc[mi][ni][3]);
            size_t addr = (((size_t)b * 128 + oc) * Ho + 2 * hin + aa) * Wo
                        + 2 * win0 + (dd ? 4 : 0);
            *(float4*)&out[addr] = o;
        }
    }
}

// ---------------------------------------------------------------------------
// bf16 flash attention: swapped-QK^T, exp2, cvt_pk, XCD grid, setprio,
// DOUBLE-BUFFERED K/V (80 KB LDS) -> single barrier per chunk.
// P-scratch is wave-private (lgkmcnt-ordered), needs no barrier.
// ---------------------------------------------------------------------------
__global__ __launch_bounds__(256, 2) void k_attn_bf16(
        const unsigned short* __restrict__ qb, const unsigned short* __restrict__ kb,
        const unsigned short* __restrict__ vt, unsigned short* __restrict__ aout) {
    __shared__ __align__(16) unsigned short smem[40960];  // 80 KB
    // layout: Ks0 | Ks1 | Vt0 | Vt1 | Ps   (8192 u16 each)
    int tid = threadIdx.x;
    int lane = tid & 63, w = tid >> 6;
    int l16 = lane & 15, lhi = lane >> 4;
    int bid = blockIdx.x;
    int xcd = bid & 7, j = bid >> 3;
    int hz = xcd * 8 + (j >> 4);
    int qt = j & 15;
    int h = hz & 3, z = hz >> 2;
    int bh_q = (z & 7) * 4 + h;
    int bh_kv = z * 4 + h;
    unsigned short* Pw = smem + 32768 + w * 2048;

    const unsigned short* qg = qb + ((size_t)bh_q * 2048 + qt * 128) * 128;
    bf16x8 qa[2][4];
#pragma unroll
    for (int mt = 0; mt < 2; mt++) {
        int r = w * 32 + mt * 16 + l16;
#pragma unroll
        for (int ks = 0; ks < 4; ks++)
            qa[mt][ks] = *(const bf16x8*)&qg[(size_t)r * 128 + ks * 32 + lhi * 8];
    }

    f32x4 acc[2][8];
#pragma unroll
    for (int mt = 0; mt < 2; mt++)
#pragma unroll
        for (int dt = 0; dt < 8; dt++) acc[mt][dt] = (f32x4){0.f, 0.f, 0.f, 0.f};
    float m_r[2] = {-1e30f, -1e30f};
    float l_r[2] = {0.f, 0.f};

    const unsigned short* kg = kb + (size_t)bh_kv * 131072;
    const unsigned short* vg = vt + (size_t)bh_kv * 131072;

    int krow = tid >> 4, kcol = (tid & 15) * 8;
    int kls = ((tid & 15) ^ (krow & 7)) << 3;
    int vrow = tid >> 3, vcol = (tid & 7) * 8;
    int vls = ((tid & 7) ^ (vrow & 7)) << 3;

    // prologue: stage chunk 0 into buffer 0
#pragma unroll
    for (int jj = 0; jj < 4; jj++) {
        int r = krow + jj * 16;
        *(bf16x8*)&smem[r * 128 + kls] = *(const bf16x8*)&kg[(size_t)r * 128 + kcol];
        int d = vrow + jj * 32;
        *(bf16x8*)&smem[16384 + d * 64 + vls] = *(const bf16x8*)&vg[(size_t)d * 1024 + vcol];
    }
    __syncthreads();

    for (int c = 0; c < 16; c++) {
        unsigned short* Ks = smem + (c & 1) * 8192;
        unsigned short* Vt2 = smem + 16384 + (c & 1) * 8192;
        unsigned short* Ksn = smem + ((c + 1) & 1) * 8192;
        unsigned short* Vtn = smem + 16384 + ((c + 1) & 1) * 8192;

        bf16x8 kpre[4], vpre[4];
        if (c < 15) {
            int c0 = (c + 1) * 64;
#pragma unroll
            for (int jj = 0; jj < 4; jj++) {
                kpre[jj] = *(const bf16x8*)&kg[(size_t)(c0 + krow + jj * 16) * 128 + kcol];
                vpre[jj] = *(const bf16x8*)&vg[(size_t)(vrow + jj * 32) * 1024 + c0 + vcol];
            }
        }

        // QK^T swapped: S^T[key][q]
        f32x4 s[2][4];
#pragma unroll
        for (int mt = 0; mt < 2; mt++)
#pragma unroll
            for (int kt = 0; kt < 4; kt++) s[mt][kt] = (f32x4){0.f, 0.f, 0.f, 0.f};
        __builtin_amdgcn_s_setprio(1);
#pragma unroll
        for (int kt = 0; kt < 4; kt++) {
            int r = kt * 16 + l16;
#pragma unroll
            for (int ks = 0; ks < 4; ks++) {
                bf16x8 kf = *(bf16x8*)&Ks[r * 128 + (((ks * 4 + lhi) ^ (r & 7)) << 3)];
                s[0][kt] = __builtin_amdgcn_mfma_f32_16x16x32_bf16(kf, qa[0][ks], s[0][kt], 0, 0, 0);
                s[1][kt] = __builtin_amdgcn_mfma_f32_16x16x32_bf16(kf, qa[1][ks], s[1][kt], 0, 0, 0);
            }
        }
        __builtin_amdgcn_s_setprio(0);

        float pm[2];
#pragma unroll
        for (int mt = 0; mt < 2; mt++) {
            float a = s[mt][0][0];
#pragma unroll
            for (int kt = 0; kt < 4; kt++)
#pragma unroll
                for (int rg = 0; rg < 4; rg++) a = fmaxf(a, s[mt][kt][rg]);
            a = fmaxf(a, __shfl_xor(a, 16));
            a = fmaxf(a, __shfl_xor(a, 32));
            pm[mt] = a;
        }
        bool need = (pm[0] > m_r[0] + 8.f) || (pm[1] > m_r[1] + 8.f);
        if (__any(need)) {
#pragma unroll
            for (int mt = 0; mt < 2; mt++) {
                float mn = fmaxf(m_r[mt], pm[mt]);
                float f = __builtin_amdgcn_exp2f(m_r[mt] - mn);
                m_r[mt] = mn;
                l_r[mt] *= f;
#pragma unroll
                for (int rg = 0; rg < 4; rg++) {
                    float ft = __shfl(f, lhi * 4 + rg);
#pragma unroll
                    for (int dt = 0; dt < 8; dt++) acc[mt][dt][rg] *= ft;
                }
            }
        }

#pragma unroll
        for (int mt = 0; mt < 2; mt++) {
            int row = mt * 16 + l16;
            int rsw = row & 7;
            float ls = 0.f;
#pragma unroll
            for (int kt = 0; kt < 4; kt++) {
                float p0 = __builtin_amdgcn_exp2f(s[mt][kt][0] - m_r[mt]);
                float p1 = __builtin_amdgcn_exp2f(s[mt][kt][1] - m_r[mt]);
                float p2 = __builtin_amdgcn_exp2f(s[mt][kt][2] - m_r[mt]);
                float p3 = __builtin_amdgcn_exp2f(s[mt][kt][3] - m_r[mt]);
                ls += (p0 + p1) + (p2 + p3);
                unsigned u01, u23;
                asm("v_cvt_pk_bf16_f32 %0, %1, %2" : "=v"(u01) : "v"(p0), "v"(p1));
                asm("v_cvt_pk_bf16_f32 %0, %1, %2" : "=v"(u23) : "v"(p2), "v"(p3));
                int slot = kt * 2 + (lhi >> 1);
                int base = row * 64 + ((slot ^ rsw) << 3) + (lhi & 1) * 4;
                *(unsigned*)&Pw[base] = u01;
                *(unsigned*)&Pw[base + 2] = u23;
            }
            l_r[mt] += ls;
        }
        asm volatile("s_waitcnt lgkmcnt(0)" ::: "memory");

        bf16x8 pa0[2], pa1[2];
#pragma unroll
        for (int mt = 0; mt < 2; mt++) {
            int row = mt * 16 + l16;
            pa0[mt] = *(bf16x8*)&Pw[row * 64 + ((lhi ^ (row & 7)) << 3)];
            pa1[mt] = *(bf16x8*)&Pw[row * 64 + (((4 + lhi) ^ (row & 7)) << 3)];
        }
        __builtin_amdgcn_s_setprio(1);
#pragma unroll
        for (int dt = 0; dt < 8; dt++) {
            int d = dt * 16 + l16;
            bf16x8 vb0 = *(bf16x8*)&Vt2[d * 64 + ((lhi ^ (d & 7)) << 3)];
            bf16x8 vb1 = *(bf16x8*)&Vt2[d * 64 + (((4 + lhi) ^ (d & 7)) << 3)];
            acc[0][dt] = __builtin_amdgcn_mfma_f32_16x16x32_bf16(pa0[0], vb0, acc[0][dt], 0, 0, 0);
            acc[0][dt] = __builtin_amdgcn_mfma_f32_16x16x32_bf16(pa1[0], vb1, acc[0][dt], 0, 0, 0);
            acc[1][dt] = __builtin_amdgcn_mfma_f32_16x16x32_bf16(pa0[1], vb0, acc[1][dt], 0, 0, 0);
            acc[1][dt] = __builtin_amdgcn_mfma_f32_16x16x32_bf16(pa1[1], vb1, acc[1][dt], 0, 0, 0);
        }
        __builtin_amdgcn_s_setprio(0);

        // write prefetched chunk into the OTHER buffer (no readers), then the
        // single barrier makes it visible for the next iteration.
        if (c < 15) {
#pragma unroll
            for (int jj = 0; jj < 4; jj++) {
                *(bf16x8*)&Ksn[(krow + jj * 16) * 128 + kls] = kpre[jj];
                *(bf16x8*)&Vtn[(vrow + jj * 32) * 64 + vls] = vpre[jj];
            }
        }
        __syncthreads();
    }

#pragma unroll
    for (int mt = 0; mt < 2; mt++) {
        float lt = l_r[mt];
        lt += __shfl_xor(lt, 16);
        lt += __shfl_xor(lt, 32);
        l_r[mt] = lt;
    }
    size_t obase = (size_t)(z >> 3) * 16384 + (size_t)(z & 7) * 2048;
#pragma unroll
    for (int mt = 0; mt < 2; mt++)
#pragma unroll
        for (int rg = 0; rg < 4; rg++) {
            float linv = 1.f / __shfl(l_r[mt], lhi * 4 + rg);
            int qrow = qt * 128 + w * 32 + mt * 16 + lhi * 4 + rg;
            unsigned short* orow = aout + (obase + qrow) * 512 + h * 128;
#pragma unroll
            for (int dt = 0; dt < 8; dt++)
                orow[dt * 16 + l16] = f2bf(acc[mt][dt][rg] * linv);
        }
}

// ---------------------------------------------------------------------------
// fused_s write + stats partials in one pass. grid (16, 8).
// ---------------------------------------------------------------------------
__global__ void k_fused_stats(const float* __restrict__ zc, const float* __restrict__ zl,
                              float* __restrict__ fs, float* __restrict__ part) {
    int c = blockIdx.x, b = blockIdx.y;
    int tid = threadIdx.x;
    int d = tid & 127, half = tid >> 7;
    size_t base0 = ((size_t)b * 2048 + c * 64) * 128;
    size_t base1 = ((size_t)b * 2048 + 1024 + c * 64) * 128;
    float s = 0.f, s2 = 0.f;
    for (int t = half; t < 64; t += 2) {
        float v = zc[base0 + t * 128 + d] + zc[base1 + t * 128 + d]
                + zl[base0 + t * 128 + d] + zl[base1 + t * 128 + d];
        fs[((size_t)b * 1024 + c * 64 + t) * 128 + d] = v;
        s += v; s2 += v * v;
    }
    __shared__ float ls[256], ls2[256];
    ls[tid] = s; ls2[tid] = s2;
    __syncthreads();
    if (tid < 128) {
        s = ls[tid] + ls[tid + 128];
        s2 = ls2[tid] + ls2[tid + 128];
        float* p = part + ((size_t)(b * 16 + c) * 2) * 128;
        p[d] = s; p[128 + d] = s2;
    }
}

// ---------------------------------------------------------------------------
extern "C" void kernel_launch(void* const* d_in, const int* in_sizes, int n_in,
                              void* d_out, int out_size, void* d_ws, size_t ws_size,
                              hipStream_t stream) {
    const float* cam_feat = (const float*)d_in[0];
    const float* lid_feat = (const float*)d_in[1];
    const float* pos      = (const float*)d_in[2];
    const float* conv_w   = (const float*)d_in[3];
    const float* convT_w  = (const float*)d_in[4];
    const float* lnq_g = (const float*)d_in[5];
    const float* lnq_b = (const float*)d_in[6];
    const float* wq    = (const float*)d_in[7];
    const float* lnk_g = (const float*)d_in[8];
    const float* lnk_b = (const float*)d_in[9];
    const float* wk    = (const float*)d_in[10];
    const float* lnv_g = (const float*)d_in[11];
    const float* lnv_b = (const float*)d_in[12];
    const float* wv    = (const float*)d_in[13];
    const float* proj_w = (const float*)d_in[14];
    const float* proj_b = (const float*)d_in[15];
    const float* pre_g = (const float*)d_in[16];
    const float* pre_b = (const float*)d_in[17];
    const float* mlp_w1 = (const float*)d_in[18];
    const float* mlp_b1 = (const float*)d_in[19];
    const float* mlp_w2 = (const float*)d_in[20];
    const float* mlp_b2 = (const float*)d_in[21];
    const float* post_g = (const float*)d_in[22];
    const float* post_b = (const float*)d_in[23];

    float* ws = (float*)d_ws;
    float* outp = (float*)d_out;

    // persistent buffers (floats)
    float* cam_eT  = ws + 0;               // 1,048,576
    float* lid_eT  = ws + 1048576;         // 1,048,576
    unsigned short* qbf16 = (unsigned short*)(ws + 2097152);   // 4,194,304 f
    float* z_cam   = ws + 6291456;         // 2,097,152
    float* z_lid   = ws + 8388608;         // 2,097,152
    float* fused_s = ws + 10485760;        // 1,048,576
    float* stats   = ws + 11534336;        // 16,384
    unsigned short* wbuf = (unsigned short*)(ws + 11550720);   // 196,608 f
    float* part    = ws + 11747328;        // 131,072
    float* mean_e  = ws + 11878400;        // 16,384
    float* rstd_e  = ws + 11894784;        // 16,384
    float* bvecs   = ws + 11911168;        // 1,536
    unsigned short* xcolT = (unsigned short*)(ws + 11912704);  // 4,194,304 f
    float* pool    = ws + 16107008;        // 16,777,216

    unsigned short* wqT   = wbuf + 0;
    unsigned short* wkT   = wbuf + 65536;
    unsigned short* wvT   = wbuf + 131072;
    unsigned short* projT = wbuf + 196608;
    unsigned short* m1T   = wbuf + 262144;
    unsigned short* m2T   = wbuf + 294912;
    unsigned short* ctT   = wbuf + 327680;

    float* meanA = stats + 0,    *rstdA = stats + 2048;
    float* meanF = stats + 4096, *rstdF = stats + 5120;

    // pool (timeline-overlapped)
    unsigned short* kbf16 = (unsigned short*)(pool + 0);        // 4,194,304 f
    unsigned short* vbfT  = (unsigned short*)(pool + 4194304);  // 4,194,304 f
    unsigned short* abuf  = (unsigned short*)(pool + 8388608);  // 8,388,608 f

    // 1/sqrt(128) * log2(e): attention softmax runs in the exp2 domain
    const float qscale = 0.12751744436f;

    // Weight prep + bias vectors (one launch)
    k_wtrans_all<<<390, TPB, 0, stream>>>(wq, wk, wv, proj_w, mlp_w1, mlp_w2, convT_w,
                                          lnq_g, lnk_g, lnv_g, lnq_b, lnk_b, lnv_b,
                                          wqT, wkT, wvT, projT, m1T, m2T, ctT, bvecs);

    // Stage A: stats + conv encoders (conv epilogue emits per-token LN stats)
    k_stats_cm<<<2048, TPB, 0, stream>>>(cam_feat, lid_feat, pos, meanA, rstdA);
    k_prep<<<dim3(32, 16), TPB, 0, stream>>>(cam_feat, lid_feat, pos, meanA, rstdA, xcolT);
    k_conv_gemm<<<dim3(16, 1, 16), TPB, 0, stream>>>(conv_w, xcolT, cam_eT, lid_eT,
                                                     mean_e, rstd_e);

    // Q/K/V; attention; fused tail (proj+preLN+mlp1+mlp2+postLN+stats)
    k_qkv_gemm<<<dim3(12, 128), TPB, 0, stream>>>(
        cam_eT, lid_eT, mean_e, rstd_e, wqT, wkT, wvT, qbf16, kbf16, vbfT,
        bvecs, qscale);
    k_attn_bf16<<<1024, TPB, 0, stream>>>(qbf16, kbf16, vbfT, abuf);
    k_tail_fused<<<512, TPB, 0, stream>>>(
        abuf, projT, m1T, m2T, cam_eT, lid_eT, proj_b, pre_g, pre_b,
        mlp_b1, mlp_b2, post_g, post_b, z_cam, z_lid, part);

    // Outputs
    k_stats_red2<<<16, 128, 0, stream>>>(part, stats + 6144, stats + 7168,
                                         stats + 8192, stats + 9216);
    k_fused_stats<<<dim3(16, 8), TPB, 0, stream>>>(z_cam, z_lid, fused_s, part + 65536);
    k_stats_red<<<8, 128, 0, stream>>>(part + 65536, meanF, rstdF, 16, 1024);
    k_convt_gemm<<<dim3(4, 40, 8), TPB, 0, stream>>>(fused_s, z_cam, z_lid, stats,
                                                     ctT, outp);
}

// Round 17
// 267.020 us; speedup vs baseline: 19.2756x; 1.0010x over previous
//
#include <hip/hip_runtime.h>
#include <math.h>

#define TPB 256

typedef __attribute__((ext_vector_type(8))) short bf16x8;
typedef __attribute__((ext_vector_type(4))) float f32x4;

__device__ __forceinline__ float gelu_exact(float x) {
    return 0.5f * x * (1.0f + erff(x * 0.70710678118654752f));
}

__device__ __forceinline__ unsigned short f2bf(float x) {
    unsigned u = __float_as_uint(x);
    return (unsigned short)((u + 0x7fffu + ((u >> 16) & 1u)) >> 16);
}

// ---------------------------------------------------------------------------
// Stage-A instance-norm stats (x + pos broadcast), 2048 channels.
// ---------------------------------------------------------------------------
__global__ void k_stats_cm(const float* __restrict__ x0, const float* __restrict__ x1,
                           const float* __restrict__ pos, float* __restrict__ mean,
                           float* __restrict__ rstd) {
    int gc = blockIdx.x;
    const float* src = ((gc < 1024) ? x0 : x1) + (size_t)(gc & 1023) * 4096;
    const float* posr = pos + (size_t)(gc & 127) * 4096;
    float s = 0.f, s2 = 0.f;
    for (int p = threadIdx.x; p < 4096; p += TPB) {
        float v = src[p] + posr[p];
        s += v; s2 += v * v;
    }
#pragma unroll
    for (int m = 32; m; m >>= 1) { s += __shfl_xor(s, m); s2 += __shfl_xor(s2, m); }
    __shared__ float ls[4], ls2[4];
    int w = threadIdx.x >> 6;
    if ((threadIdx.x & 63) == 0) { ls[w] = s; ls2[w] = s2; }
    __syncthreads();
    if (threadIdx.x == 0) {
        s = ls[0] + ls[1] + ls[2] + ls[3];
        s2 = ls2[0] + ls2[1] + ls2[2] + ls2[3];
        float mu = s / 4096.f;
        float var = s2 / 4096.f - mu * mu;
        mean[gc] = mu;
        rstd[gc] = rsqrtf(var + 1e-5f);
    }
}

// ---------------------------------------------------------------------------
// Token-major stats reduces.
// ---------------------------------------------------------------------------
__global__ void k_stats_red(const float* __restrict__ part, float* __restrict__ mean,
                            float* __restrict__ rstd, int nc, int T) {
    int b = blockIdx.x, d = threadIdx.x;
    float s = 0.f, s2 = 0.f;
    for (int c = 0; c < nc; c++) {
        const float* p = part + ((size_t)(b * nc + c) * 2) * 128;
        s += p[d]; s2 += p[128 + d];
    }
    float mu = s / (float)T;
    float var = s2 / (float)T - mu * mu;
    mean[b * 128 + d] = mu;
    rstd[b * 128 + d] = rsqrtf(var + 1e-5f);
}

__global__ void k_stats_red2(const float* __restrict__ part,
                             float* __restrict__ meanC, float* __restrict__ rstdC,
                             float* __restrict__ meanL, float* __restrict__ rstdL) {
    int idx = blockIdx.x, d = threadIdx.x;
    int sel = idx >> 3, b = idx & 7;
    float s = 0.f, s2 = 0.f;
    for (int c = 0; c < 32; c++) {
        const float* p = part + ((size_t)((sel * 8 + b) * 32 + c) * 2) * 128;
        s += p[d]; s2 += p[128 + d];
    }
    float mu = s / 2048.f;
    float var = s2 / 2048.f - mu * mu;
    float* mean = sel ? meanL : meanC;
    float* rstd = sel ? rstdL : rstdC;
    mean[b * 128 + d] = mu;
    rstd[b * 128 + d] = rsqrtf(var + 1e-5f);
}

// ---------------------------------------------------------------------------
// Conv prep (cam+lid merged): normalize+ReLU+im2col -> bf16 xcolT[bb][p][512].
// ---------------------------------------------------------------------------
__global__ void k_prep(const float* __restrict__ cam, const float* __restrict__ lid,
                       const float* __restrict__ pos, const float* __restrict__ mean,
                       const float* __restrict__ rstd, unsigned short* __restrict__ xcolT) {
    __shared__ unsigned short T[32 * 520];
    int h = blockIdx.x, bb = blockIdx.y;
    int b = bb & 7, so = (bb < 8) ? 0 : 1024;
    const float* x = (bb < 8) ? cam : lid;
    int tid = threadIdx.x;
    for (int i = tid; i < 4096; i += TPB) {
        int c = i >> 5, w = i & 31;
        int ch = b * 128 + c;
        const float* xr = x + (size_t)ch * 4096 + (2 * h) * 64 + 2 * w;
        const float* pr = pos + (size_t)c * 4096 + (2 * h) * 64 + 2 * w;
        float mu = mean[so + ch], rs = rstd[so + ch];
        float2 x0 = *(const float2*)xr;
        float2 x1 = *(const float2*)(xr + 64);
        float2 p0 = *(const float2*)pr;
        float2 p1 = *(const float2*)(pr + 64);
        ushort4 u;
        u.x = f2bf(fmaxf((x0.x + p0.x - mu) * rs, 0.f));
        u.y = f2bf(fmaxf((x0.y + p0.y - mu) * rs, 0.f));
        u.z = f2bf(fmaxf((x1.x + p1.x - mu) * rs, 0.f));
        u.w = f2bf(fmaxf((x1.y + p1.y - mu) * rs, 0.f));
        *(ushort4*)&T[w * 520 + c * 4] = u;
    }
    __syncthreads();
    unsigned short* dst = xcolT + ((size_t)bb * 1024 + h * 32) * 512;
    for (int i = tid; i < 2048; i += TPB) {
        int w = i >> 6, kk = (i & 63) * 8;
        *(bf16x8*)&dst[(size_t)w * 512 + kk] = *(bf16x8*)&T[w * 520 + kk];
    }
}

// ---------------------------------------------------------------------------
// Conv as batched MFMA GEMM (cam+lid merged) + per-token LN stats epilogue.
// grid (16, 1, 16).
// ---------------------------------------------------------------------------
__global__ __launch_bounds__(256, 2) void k_conv_gemm(
        const float* __restrict__ W, const unsigned short* __restrict__ xcolT,
        float* __restrict__ camT, float* __restrict__ lidT,
        float* __restrict__ mean_e, float* __restrict__ rstd_e) {
    __shared__ __align__(16) unsigned short As[128 * 40];
    __shared__ __align__(16) unsigned short Bs[64 * 40];
    __shared__ float red[2048];
    int tid = threadIdx.x, lane = tid & 63, w = tid >> 6;
    int l16 = lane & 15, lhi = lane >> 4;
    int n0 = blockIdx.x * 64, bb = blockIdx.z;
    const unsigned short* BT = xcolT + (size_t)bb * 524288;
    float* eT = ((bb < 8) ? camT : lidT) + (size_t)(bb & 7) * 131072;

    f32x4 acc[2][4];
#pragma unroll
    for (int mi = 0; mi < 2; mi++)
#pragma unroll
        for (int ni = 0; ni < 4; ni++) acc[mi][ni] = (f32x4){0.f, 0.f, 0.f, 0.f};

    for (int k0 = 0; k0 < 512; k0 += 32) {
        for (int i = tid; i < 1024; i += TPB) {
            int row = i >> 3, kc = (i & 7) * 4;
            float4 va = *(const float4*)&W[(size_t)row * 512 + k0 + kc];
            ushort4 u;
            u.x = f2bf(va.x); u.y = f2bf(va.y); u.z = f2bf(va.z); u.w = f2bf(va.w);
            *(ushort4*)&As[row * 40 + kc] = u;
        }
        for (int i = tid; i < 256; i += TPB) {
            int n = i >> 2, kc = (i & 3) * 8;
            *(bf16x8*)&Bs[n * 40 + kc] = *(const bf16x8*)&BT[(size_t)(n0 + n) * 512 + k0 + kc];
        }
        __syncthreads();
        bf16x8 af[2], bfr[4];
#pragma unroll
        for (int mi = 0; mi < 2; mi++)
            af[mi] = *(bf16x8*)&As[(w * 32 + mi * 16 + l16) * 40 + lhi * 8];
#pragma unroll
        for (int ni = 0; ni < 4; ni++)
            bfr[ni] = *(bf16x8*)&Bs[(ni * 16 + l16) * 40 + lhi * 8];
#pragma unroll
        for (int mi = 0; mi < 2; mi++)
#pragma unroll
            for (int ni = 0; ni < 4; ni++)
                acc[mi][ni] = __builtin_amdgcn_mfma_f32_16x16x32_bf16(af[mi], bfr[ni], acc[mi][ni], 0, 0, 0);
        __syncthreads();
    }
#pragma unroll
    for (int mi = 0; mi < 2; mi++)
#pragma unroll
        for (int ni = 0; ni < 4; ni++) {
            int col = n0 + ni * 16 + l16;
            int rowb = w * 32 + mi * 16 + lhi * 4;
            *(float4*)&eT[(size_t)col * 128 + rowb] = *(float4*)&acc[mi][ni];
        }
#pragma unroll
    for (int ni = 0; ni < 4; ni++) {
        float s = 0.f, s2 = 0.f;
#pragma unroll
        for (int mi = 0; mi < 2; mi++)
#pragma unroll
            for (int rg = 0; rg < 4; rg++) {
                float v = acc[mi][ni][rg];
                s += v; s2 += v * v;
            }
        int idx = (ni * 16 + l16) * 16 + w * 4 + lhi;
        red[idx] = s;
        red[1024 + idx] = s2;
    }
    __syncthreads();
    if (tid < 64) {
        int ni = tid >> 4, c16 = tid & 15;
        float s = 0.f, s2 = 0.f;
#pragma unroll
        for (int j = 0; j < 16; j++) {
            s += red[(ni * 16 + c16) * 16 + j];
            s2 += red[1024 + (ni * 16 + c16) * 16 + j];
        }
        int col = n0 + ni * 16 + c16;
        int tok = bb * 1024 + col;
        float mu = s * (1.f / 128.f);
        float var = s2 * (1.f / 128.f) - mu * mu;
        mean_e[tok] = mu;
        rstd_e[tok] = rsqrtf(var + 1e-5f);
    }
}

// ---------------------------------------------------------------------------
// Weight transposes (bid<384, gamma-prescaled Q/K/V) + beta@W bias vectors
// (bid 384..389) in ONE launch. grid 390.
// ---------------------------------------------------------------------------
__global__ void k_wtrans_all(
        const float* __restrict__ wq, const float* __restrict__ wk,
        const float* __restrict__ wv, const float* __restrict__ proj,
        const float* __restrict__ m1, const float* __restrict__ m2,
        const float* __restrict__ ct,
        const float* __restrict__ gq, const float* __restrict__ gk,
        const float* __restrict__ gv,
        const float* __restrict__ bq_in, const float* __restrict__ bk_in,
        const float* __restrict__ bv_in,
        unsigned short* wqT, unsigned short* wkT, unsigned short* wvT,
        unsigned short* projT, unsigned short* m1T, unsigned short* m2T,
        unsigned short* ctT, float* __restrict__ bout) {
    __shared__ float t[32][33];
    int bid = blockIdx.x;
    int tid = threadIdx.x;
    if (bid >= 384) {
        int i = bid - 384;
        int which = i >> 1, half = i & 1;
        const float* W = (which == 0) ? wq : (which == 1) ? wk : wv;
        const float* bb = (which == 0) ? bq_in : (which == 1) ? bk_in : bv_in;
        int n = half * 256 + tid;
        float s = 0.f;
        for (int k = 0; k < 128; k++) s += bb[k] * W[(size_t)k * 512 + n];
        bout[which * 512 + n] = s;
        return;
    }
    const float* W; unsigned short* WT; const float* sc = nullptr; int K, N, ti;
    if (bid < 64)       { W = wq;   WT = wqT;   sc = gq; K = 128; N = 512; ti = bid; }
    else if (bid < 128) { W = wk;   WT = wkT;   sc = gk; K = 128; N = 512; ti = bid - 64; }
    else if (bid < 192) { W = wv;   WT = wvT;   sc = gv; K = 128; N = 512; ti = bid - 128; }
    else if (bid < 256) { W = proj; WT = projT; K = 512; N = 128; ti = bid - 192; }
    else if (bid < 288) { W = m1;   WT = m1T;   K = 128; N = 256; ti = bid - 256; }
    else if (bid < 320) { W = m2;   WT = m2T;   K = 256; N = 128; ti = bid - 288; }
    else                { W = ct;   WT = ctT;   K = 128; N = 512; ti = bid - 320; }
    int tx = N >> 5;
    int n0 = (ti % tx) * 32, k0 = (ti / tx) * 32;
    for (int i = tid; i < 1024; i += TPB) {
        int r = i >> 5, c = i & 31;
        float v = W[(size_t)(k0 + r) * N + n0 + c];
        if (sc) v *= sc[k0 + r];
        t[r][c] = v;
    }
    __syncthreads();
    for (int i = tid; i < 1024; i += TPB) {
        int r = i >> 5, c = i & 31;
        WT[(size_t)(n0 + r) * K + k0 + c] = f2bf(t[c][r]);
    }
}

// ---------------------------------------------------------------------------
// Merged Q/K/V projection GEMM with fused LN on A. grid (12, 128).
// ---------------------------------------------------------------------------
__global__ __launch_bounds__(256, 2) void k_qkv_gemm(
        const float* __restrict__ camT, const float* __restrict__ lidT,
        const float* __restrict__ me, const float* __restrict__ re,
        const unsigned short* __restrict__ wqT, const unsigned short* __restrict__ wkT,
        const unsigned short* __restrict__ wvT,
        unsigned short* __restrict__ qout, unsigned short* __restrict__ kout,
        unsigned short* __restrict__ vout,
        const float* __restrict__ bvecs, float qscale) {
    __shared__ __align__(16) unsigned short As[128 * 40];
    __shared__ __align__(16) unsigned short Bs[128 * 40];
    int tid = threadIdx.x, lane = tid & 63, w = tid >> 6;
    int l16 = lane & 15, lhi = lane >> 4;
    int wm = w >> 1, wn = w & 1;
    int which = blockIdx.x >> 2;
    int n0 = (blockIdx.x & 3) * 128;
    int m0 = blockIdx.y * 128;
    const unsigned short* BT = (which == 0) ? wqT : (which == 1) ? wkT : wvT;
    const float* bias = bvecs + which * 512;

    f32x4 acc[4][4];
#pragma unroll
    for (int mi = 0; mi < 4; mi++)
#pragma unroll
        for (int ni = 0; ni < 4; ni++) acc[mi][ni] = (f32x4){0.f, 0.f, 0.f, 0.f};

    for (int k0 = 0; k0 < 128; k0 += 32) {
        for (int i = tid; i < 1024; i += TPB) {
            int row = i >> 3, kc = (i & 7) * 4;
            int r = m0 + row;
            const float* srow;
            int tok;
            if (which == 0) {
                int b = r >> 11, t = r & 2047;
                bool cam = t < 1024;
                tok = (cam ? b : 8 + b) * 1024 + (t & 1023);
                srow = (cam ? camT : lidT) + (size_t)(b * 1024 + (t & 1023)) * 128;
            } else {
                tok = r;
                srow = ((r < 8192) ? camT : lidT) + (size_t)(r & 8191) * 128;
            }
            float mu = me[tok], rs = re[tok];
            float4 va = *(const float4*)&srow[k0 + kc];
            ushort4 u;
            u.x = f2bf((va.x - mu) * rs); u.y = f2bf((va.y - mu) * rs);
            u.z = f2bf((va.z - mu) * rs); u.w = f2bf((va.w - mu) * rs);
            *(ushort4*)&As[row * 40 + kc] = u;
        }
        for (int i = tid; i < 512; i += TPB) {
            int n = i >> 2, kc = (i & 3) * 8;
            *(bf16x8*)&Bs[n * 40 + kc] = *(const bf16x8*)&BT[(size_t)(n0 + n) * 128 + k0 + kc];
        }
        __syncthreads();
        bf16x8 af[4], bfr[4];
#pragma unroll
        for (int mi = 0; mi < 4; mi++)
            af[mi] = *(bf16x8*)&As[(wm * 64 + mi * 16 + l16) * 40 + lhi * 8];
#pragma unroll
        for (int ni = 0; ni < 4; ni++)
            bfr[ni] = *(bf16x8*)&Bs[(wn * 64 + ni * 16 + l16) * 40 + lhi * 8];
#pragma unroll
        for (int mi = 0; mi < 4; mi++)
#pragma unroll
            for (int ni = 0; ni < 4; ni++)
                acc[mi][ni] = __builtin_amdgcn_mfma_f32_16x16x32_bf16(af[mi], bfr[ni], acc[mi][ni], 0, 0, 0);
        __syncthreads();
    }
#pragma unroll
    for (int mi = 0; mi < 4; mi++) {
#pragma unroll
        for (int ni = 0; ni < 4; ni++) {
            int col = n0 + wn * 64 + ni * 16 + l16;
            float bc = bias[col];
            if (which == 2) {
                int row0 = m0 + wm * 64 + mi * 16 + lhi * 4;
                int bb = row0 >> 10, t0 = row0 & 1023;
                ushort4 u;
                u.x = f2bf(acc[mi][ni][0] + bc); u.y = f2bf(acc[mi][ni][1] + bc);
                u.z = f2bf(acc[mi][ni][2] + bc); u.w = f2bf(acc[mi][ni][3] + bc);
                *(ushort4*)&vout[(((size_t)(bb * 4 + (col >> 7))) * 128 + (col & 127)) * 1024 + t0] = u;
            } else {
                int sT = (which == 0) ? 11 : 10;
                float sc = (which == 0) ? qscale : 1.f;
                unsigned short* C16 = (which == 0) ? qout : kout;
#pragma unroll
                for (int rg = 0; rg < 4; rg++) {
                    int row = m0 + wm * 64 + mi * 16 + lhi * 4 + rg;
                    int bb = row >> sT, t = row & ((1 << sT) - 1);
                    size_t oa = ((((size_t)bb * 4 + (col >> 7)) << sT) + t) * 128 + (col & 127);
                    C16[oa] = f2bf((acc[mi][ni][rg] + bc) * sc);
                }
            }
        }
    }
}

// ---------------------------------------------------------------------------
// FUSED TAIL: proj+preLN+mlp1+mlp2+postLN -> fp32 z outputs + stats partials.
// ---------------------------------------------------------------------------
__global__ __launch_bounds__(256, 2) void k_tail_fused(
        const unsigned short* __restrict__ abuf, const unsigned short* __restrict__ projT,
        const unsigned short* __restrict__ m1T, const unsigned short* __restrict__ m2T,
        const float* __restrict__ camT, const float* __restrict__ lidT,
        const float* __restrict__ proj_b,
        const float* __restrict__ pre_g, const float* __restrict__ pre_b,
        const float* __restrict__ mlp_b1, const float* __restrict__ mlp_b2,
        const float* __restrict__ post_g, const float* __restrict__ post_b,
        float* __restrict__ z_cam, float* __restrict__ z_lid,
        float* __restrict__ part) {
    __shared__ __align__(16) unsigned short shm[21504];  // 43 KB
    int tid = threadIdx.x, lane = tid & 63, w = tid >> 6;
    int l16 = lane & 15, lhi = lane >> 4;
    int m0 = blockIdx.x * 64;
    int tok = w * 16 + l16;
    int grow = m0 + tok;
    int tsw = tok & 7;

    // ---- Phase 1: proj GEMM (K=512), swapped: D[col n][tok] ----
    unsigned short* Ts = shm;          // [64][40]
    unsigned short* Ws = shm + 2560;   // [128][40]
    f32x4 z2[8];
#pragma unroll
    for (int ni = 0; ni < 8; ni++) z2[ni] = (f32x4){0.f, 0.f, 0.f, 0.f};
    for (int k0 = 0; k0 < 512; k0 += 32) {
        for (int i = tid; i < 256; i += TPB) {
            int row = i >> 2, kc = (i & 3) * 8;
            *(bf16x8*)&Ts[row * 40 + kc] =
                *(const bf16x8*)&abuf[(size_t)(m0 + row) * 512 + k0 + kc];
        }
        for (int i = tid; i < 512; i += TPB) {
            int row = i >> 2, kc = (i & 3) * 8;
            *(bf16x8*)&Ws[row * 40 + kc] =
                *(const bf16x8*)&projT[(size_t)row * 512 + k0 + kc];
        }
        __syncthreads();
        bf16x8 bfr = *(bf16x8*)&Ts[tok * 40 + lhi * 8];
#pragma unroll
        for (int ni = 0; ni < 8; ni++) {
            bf16x8 af = *(bf16x8*)&Ws[(ni * 16 + l16) * 40 + lhi * 8];
            z2[ni] = __builtin_amdgcn_mfma_f32_16x16x32_bf16(af, bfr, z2[ni], 0, 0, 0);
        }
        __syncthreads();
    }
    // epilogue 1: + proj_b + skip (width-concat [camT|lidT])
    {
        int rr = grow & 16383;
        int b = rr >> 11, ss = rr & 2047;
        int Hh = ss >> 6, Ww = ss & 63;
        const float* sp = ((Ww < 32) ? camT : lidT)
                        + ((size_t)(b * 1024 + Hh * 32 + (Ww & 31))) * 128;
#pragma unroll
        for (int ni = 0; ni < 8; ni++) {
            int c0 = ni * 16 + lhi * 4;
            float4 pb = *(const float4*)&proj_b[c0];
            float4 sk = *(const float4*)&sp[c0];
            z2[ni][0] += pb.x + sk.x; z2[ni][1] += pb.y + sk.y;
            z2[ni][2] += pb.z + sk.z; z2[ni][3] += pb.w + sk.w;
        }
    }
    // preLN (in-register): z2 <- LN(z2)  [LN'd value IS the MLP residual]
    unsigned short* z2ln = shm;  // [64][128] swizzled
    {
        float s = 0.f, s2 = 0.f;
#pragma unroll
        for (int ni = 0; ni < 8; ni++)
#pragma unroll
            for (int rg = 0; rg < 4; rg++) { float v = z2[ni][rg]; s += v; s2 += v * v; }
        s += __shfl_xor(s, 16); s2 += __shfl_xor(s2, 16);
        s += __shfl_xor(s, 32); s2 += __shfl_xor(s2, 32);
        float mu = s * (1.f / 128.f);
        float var = s2 * (1.f / 128.f) - mu * mu;
        float rs = rsqrtf(var + 1e-5f);
#pragma unroll
        for (int ni = 0; ni < 8; ni++) {
            int c0 = ni * 16 + lhi * 4;
            float4 gg = *(const float4*)&pre_g[c0];
            float4 bb = *(const float4*)&pre_b[c0];
            z2[ni][0] = (z2[ni][0] - mu) * rs * gg.x + bb.x;
            z2[ni][1] = (z2[ni][1] - mu) * rs * gg.y + bb.y;
            z2[ni][2] = (z2[ni][2] - mu) * rs * gg.z + bb.z;
            z2[ni][3] = (z2[ni][3] - mu) * rs * gg.w + bb.w;
            unsigned u01, u23;
            asm("v_cvt_pk_bf16_f32 %0, %1, %2" : "=v"(u01) : "v"(z2[ni][0]), "v"(z2[ni][1]));
            asm("v_cvt_pk_bf16_f32 %0, %1, %2" : "=v"(u23) : "v"(z2[ni][2]), "v"(z2[ni][3]));
            int slot = ni * 2 + (lhi >> 1);
            int base = tok * 128 + ((slot ^ tsw) << 3) + (lhi & 1) * 4;
            *(unsigned*)&z2ln[base] = u01;
            *(unsigned*)&z2ln[base + 2] = u23;
        }
    }

    // ---- Phase 2: mlp1 (K=128, N=256), swapped ----
    unsigned short* As1 = shm + 8192;  // [256][40]
    f32x4 a1[16];
#pragma unroll
    for (int ni = 0; ni < 16; ni++) a1[ni] = (f32x4){0.f, 0.f, 0.f, 0.f};
    for (int ks = 0; ks < 4; ks++) {
        int k0 = ks * 32;
        for (int i = tid; i < 1024; i += TPB) {
            int row = i >> 2, kc = (i & 3) * 8;
            *(bf16x8*)&As1[row * 40 + kc] =
                *(const bf16x8*)&m1T[(size_t)row * 128 + k0 + kc];
        }
        __syncthreads();
        bf16x8 bfr = *(bf16x8*)&z2ln[tok * 128 + (((ks * 4 + lhi) ^ tsw) << 3)];
#pragma unroll
        for (int ni = 0; ni < 16; ni++) {
            bf16x8 af = *(bf16x8*)&As1[(ni * 16 + l16) * 40 + lhi * 8];
            a1[ni] = __builtin_amdgcn_mfma_f32_16x16x32_bf16(af, bfr, a1[ni], 0, 0, 0);
        }
        __syncthreads();
    }
    // GELU -> h1 bf16 to LDS
    unsigned short* Hs = shm;  // [64][256] swizzled
#pragma unroll
    for (int ni = 0; ni < 16; ni++) {
        int c0 = ni * 16 + lhi * 4;
        float4 bb = *(const float4*)&mlp_b1[c0];
        float h0 = gelu_exact(a1[ni][0] + bb.x);
        float h1v = gelu_exact(a1[ni][1] + bb.y);
        float h2 = gelu_exact(a1[ni][2] + bb.z);
        float h3 = gelu_exact(a1[ni][3] + bb.w);
        unsigned u01, u23;
        asm("v_cvt_pk_bf16_f32 %0, %1, %2" : "=v"(u01) : "v"(h0), "v"(h1v));
        asm("v_cvt_pk_bf16_f32 %0, %1, %2" : "=v"(u23) : "v"(h2), "v"(h3));
        int slot = ni * 2 + (lhi >> 1);
        int base = tok * 256 + ((slot ^ tsw) << 3) + (lhi & 1) * 4;
        *(unsigned*)&Hs[base] = u01;
        *(unsigned*)&Hs[base + 2] = u23;
    }

    // ---- Phase 3: mlp2 (K=256, N=128), swapped ----
    unsigned short* As2 = shm + 16384;  // [128][40]
    f32x4 a2[8];
#pragma unroll
    for (int ni = 0; ni < 8; ni++) a2[ni] = (f32x4){0.f, 0.f, 0.f, 0.f};
    for (int ks = 0; ks < 8; ks++) {
        int k0 = ks * 32;
        for (int i = tid; i < 512; i += TPB) {
            int row = i >> 2, kc = (i & 3) * 8;
            *(bf16x8*)&As2[row * 40 + kc] =
                *(const bf16x8*)&m2T[(size_t)row * 256 + k0 + kc];
        }
        __syncthreads();
        bf16x8 bfr = *(bf16x8*)&Hs[tok * 256 + (((ks * 4 + lhi) ^ tsw) << 3)];
#pragma unroll
        for (int ni = 0; ni < 8; ni++) {
            bf16x8 af = *(bf16x8*)&As2[(ni * 16 + l16) * 40 + lhi * 8];
            a2[ni] = __builtin_amdgcn_mfma_f32_16x16x32_bf16(af, bfr, a2[ni], 0, 0, 0);
        }
        __syncthreads();
    }
    // epilogue 3: + mlp_b2 + LN'd-z2 residual -> postLN -> fp32 store + stats
    float* O = (float*)shm;  // [64][132] fp32
    {
#pragma unroll
        for (int ni = 0; ni < 8; ni++) {
            int c0 = ni * 16 + lhi * 4;
            float4 bb = *(const float4*)&mlp_b2[c0];
            a2[ni][0] += bb.x + z2[ni][0];
            a2[ni][1] += bb.y + z2[ni][1];
            a2[ni][2] += bb.z + z2[ni][2];
            a2[ni][3] += bb.w + z2[ni][3];
        }
        float s = 0.f, s2 = 0.f;
#pragma unroll
        for (int ni = 0; ni < 8; ni++)
#pragma unroll
            for (int rg = 0; rg < 4; rg++) { float v = a2[ni][rg]; s += v; s2 += v * v; }
        s += __shfl_xor(s, 16); s2 += __shfl_xor(s2, 16);
        s += __shfl_xor(s, 32); s2 += __shfl_xor(s2, 32);
        float mu = s * (1.f / 128.f);
        float var = s2 * (1.f / 128.f) - mu * mu;
        float rs = rsqrtf(var + 1e-5f);
        float* Cp = (grow < 16384) ? z_cam : z_lid;
        size_t ro = (size_t)(grow & 16383) * 128;
#pragma unroll
        for (int ni = 0; ni < 8; ni++) {
            int c0 = ni * 16 + lhi * 4;
            float4 gg = *(const float4*)&post_g[c0];
            float4 bb = *(const float4*)&post_b[c0];
            float4 o;
            o.x = (a2[ni][0] - mu) * rs * gg.x + bb.x;
            o.y = (a2[ni][1] - mu) * rs * gg.y + bb.y;
            o.z = (a2[ni][2] - mu) * rs * gg.z + bb.z;
            o.w = (a2[ni][3] - mu) * rs * gg.w + bb.w;
            *(float4*)&Cp[ro + c0] = o;
            *(float4*)&O[tok * 132 + c0] = o;
        }
    }
    __syncthreads();
    if (tid < 128) {
        int col = tid;
        float s = 0.f, s2 = 0.f;
        for (int t = 0; t < 64; t++) {
            float v = O[t * 132 + col];
            s += v; s2 += v * v;
        }
        int sel = (m0 >= 16384) ? 1 : 0;
        int rrg = m0 & 16383;
        int b = rrg >> 11, c = (rrg >> 6) & 31;
        float* p = part + ((size_t)((sel * 8 + b) * 32 + c) * 2) * 128;
        p[col] = s; p[128 + col] = s2;
    }
}

// ---------------------------------------------------------------------------
// ConvTranspose, ALL THREE outputs in one launch. grid (4, 40, 8).
// ---------------------------------------------------------------------------
__global__ __launch_bounds__(256, 2) void k_convt_gemm(
        const float* __restrict__ srcF, const float* __restrict__ srcC,
        const float* __restrict__ srcL, const float* __restrict__ stats,
        const unsigned short* __restrict__ ctT, float* __restrict__ outp) {
    __shared__ __align__(16) unsigned short As[128 * 40];
    __shared__ __align__(16) unsigned short Bs[128 * 40];
    int tid = threadIdx.x, lane = tid & 63, w = tid >> 6;
    int l16 = lane & 15, lhi = lane >> 4;
    int wm = w >> 1, wn = w & 1;
    int my = blockIdx.y, n0 = blockIdx.x * 128, b = blockIdx.z;
    const float* src; const float* mean; const float* rstd; float* out;
    int M, Hin, m0;
    if (my < 8)       { src = srcF; mean = stats + 4096; rstd = stats + 5120;
                        out = outp;            M = 1024; Hin = 32; m0 = my * 128; }
    else if (my < 24) { src = srcC; mean = stats + 6144; rstd = stats + 7168;
                        out = outp + 4194304;  M = 2048; Hin = 64; m0 = (my - 8) * 128; }
    else              { src = srcL; mean = stats + 8192; rstd = stats + 9216;
                        out = outp + 12582912; M = 2048; Hin = 64; m0 = (my - 24) * 128; }
    const float* Ab = src + (size_t)b * M * 128;
    const float* mb = mean + b * 128;
    const float* rb = rstd + b * 128;

    f32x4 acc[4][4];
#pragma unroll
    for (int mi = 0; mi < 4; mi++)
#pragma unroll
        for (int ni = 0; ni < 4; ni++) acc[mi][ni] = (f32x4){0.f, 0.f, 0.f, 0.f};

    for (int k0 = 0; k0 < 128; k0 += 32) {
        for (int i = tid; i < 1024; i += TPB) {
            int row = i >> 3, kc = (i & 7) * 4;
            float4 va = *(const float4*)&Ab[(size_t)(m0 + row) * 128 + k0 + kc];
            float4 mn = *(const float4*)&mb[k0 + kc];
            float4 rs = *(const float4*)&rb[k0 + kc];
            ushort4 u;
            u.x = f2bf(fmaxf((va.x - mn.x) * rs.x, 0.f));
            u.y = f2bf(fmaxf((va.y - mn.y) * rs.y, 0.f));
            u.z = f2bf(fmaxf((va.z - mn.z) * rs.z, 0.f));
            u.w = f2bf(fmaxf((va.w - mn.w) * rs.w, 0.f));
            *(ushort4*)&As[row * 40 + kc] = u;
        }
        for (int i = tid; i < 512; i += TPB) {
            int n = i >> 2, kc = (i & 3) * 8;
            *(bf16x8*)&Bs[n * 40 + kc] = *(const bf16x8*)&ctT[(size_t)(n0 + n) * 128 + k0 + kc];
        }
        __syncthreads();
        bf16x8 af[4], bfr[4];
#pragma unroll
        for (int mi = 0; mi < 4; mi++)
            af[mi] = *(bf16x8*)&As[(wm * 64 + mi * 16 + l16) * 40 + lhi * 8];
#pragma unroll
        for (int ni = 0; ni < 4; ni++)
            bfr[ni] = *(bf16x8*)&Bs[(wn * 64 + ni * 16 + l16) * 40 + lhi * 8];
#pragma unroll
        for (int mi = 0; mi < 4; mi++)
#pragma unroll
            for (int ni = 0; ni < 4; ni++)
                acc[mi][ni] = __builtin_amdgcn_mfma_f32_16x16x32_bf16(af[mi], bfr[ni], acc[mi][ni], 0, 0, 0);
        __syncthreads();
    }
    int Ho = 2 * Hin, Wo = 64;
#pragma unroll
    for (int mi = 0; mi < 4; mi++) {
#pragma unroll
        for (int ni = 0; ni < 4; ni++) {
            int col = n0 + wn * 64 + ni * 16 + l16;
            int oc = col >> 2, aa = (col >> 1) & 1, dd = col & 1;
            int p0 = m0 + wm * 64 + mi * 16 + lhi * 4;
            int hin = p0 >> 5, win0 = p0 & 31;
            float s0 = __shfl_xor(acc[mi][ni][0], 1);
            float s1 = __shfl_xor(acc[mi][ni][1], 1);
            float s2 = __shfl_xor(acc[mi][ni][2], 1);
            float s3 = __shfl_xor(acc[mi][ni][3], 1);
            float4 o;
            if (!dd) o = make_float4(acc[mi][ni][0], s0, acc[mi][ni][1], s1);
            else     o = make_float4(s2, acc[mi][ni][2], s3, acc[mi][ni][3]);
            size_t addr = (((size_t)b * 128 + oc) * Ho + 2 * hin + aa) * Wo
                        + 2 * win0 + (dd ? 4 : 0);
            *(float4*)&out[addr] = o;
        }
    }
}

// ---------------------------------------------------------------------------
// bf16 flash attention: swapped-QK^T, exp2, cvt_pk, XCD grid, setprio,
// DOUBLE-BUFFERED K/V via register prefetch (80 KB LDS), 1 barrier/chunk.
// (Round-14 proven version.)
// ---------------------------------------------------------------------------
__global__ __launch_bounds__(256, 2) void k_attn_bf16(
        const unsigned short* __restrict__ qb, const unsigned short* __restrict__ kb,
        const unsigned short* __restrict__ vt, unsigned short* __restrict__ aout) {
    __shared__ __align__(16) unsigned short smem[40960];  // 80 KB
    // layout: Ks0 | Ks1 | Vt0 | Vt1 | Ps   (8192 u16 each)
    int tid = threadIdx.x;
    int lane = tid & 63, w = tid >> 6;
    int l16 = lane & 15, lhi = lane >> 4;
    int bid = blockIdx.x;
    int xcd = bid & 7, j = bid >> 3;
    int hz = xcd * 8 + (j >> 4);
    int qt = j & 15;
    int h = hz & 3, z = hz >> 2;
    int bh_q = (z & 7) * 4 + h;
    int bh_kv = z * 4 + h;
    unsigned short* Pw = smem + 32768 + w * 2048;

    const unsigned short* qg = qb + ((size_t)bh_q * 2048 + qt * 128) * 128;
    bf16x8 qa[2][4];
#pragma unroll
    for (int mt = 0; mt < 2; mt++) {
        int r = w * 32 + mt * 16 + l16;
#pragma unroll
        for (int ks = 0; ks < 4; ks++)
            qa[mt][ks] = *(const bf16x8*)&qg[(size_t)r * 128 + ks * 32 + lhi * 8];
    }

    f32x4 acc[2][8];
#pragma unroll
    for (int mt = 0; mt < 2; mt++)
#pragma unroll
        for (int dt = 0; dt < 8; dt++) acc[mt][dt] = (f32x4){0.f, 0.f, 0.f, 0.f};
    float m_r[2] = {-1e30f, -1e30f};
    float l_r[2] = {0.f, 0.f};

    const unsigned short* kg = kb + (size_t)bh_kv * 131072;
    const unsigned short* vg = vt + (size_t)bh_kv * 131072;

    int krow = tid >> 4, kcol = (tid & 15) * 8;
    int kls = ((tid & 15) ^ (krow & 7)) << 3;
    int vrow = tid >> 3, vcol = (tid & 7) * 8;
    int vls = ((tid & 7) ^ (vrow & 7)) << 3;

    // prologue: stage chunk 0 into buffer 0
#pragma unroll
    for (int jj = 0; jj < 4; jj++) {
        int r = krow + jj * 16;
        *(bf16x8*)&smem[r * 128 + kls] = *(const bf16x8*)&kg[(size_t)r * 128 + kcol];
        int d = vrow + jj * 32;
        *(bf16x8*)&smem[16384 + d * 64 + vls] = *(const bf16x8*)&vg[(size_t)d * 1024 + vcol];
    }
    __syncthreads();

    for (int c = 0; c < 16; c++) {
        unsigned short* Ks = smem + (c & 1) * 8192;
        unsigned short* Vt2 = smem + 16384 + (c & 1) * 8192;
        unsigned short* Ksn = smem + ((c + 1) & 1) * 8192;
        unsigned short* Vtn = smem + 16384 + ((c + 1) & 1) * 8192;

        bf16x8 kpre[4], vpre[4];
        if (c < 15) {
            int c0 = (c + 1) * 64;
#pragma unroll
            for (int jj = 0; jj < 4; jj++) {
                kpre[jj] = *(const bf16x8*)&kg[(size_t)(c0 + krow + jj * 16) * 128 + kcol];
                vpre[jj] = *(const bf16x8*)&vg[(size_t)(vrow + jj * 32) * 1024 + c0 + vcol];
            }
        }

        // QK^T swapped: S^T[key][q]
        f32x4 s[2][4];
#pragma unroll
        for (int mt = 0; mt < 2; mt++)
#pragma unroll
            for (int kt = 0; kt < 4; kt++) s[mt][kt] = (f32x4){0.f, 0.f, 0.f, 0.f};
        __builtin_amdgcn_s_setprio(1);
#pragma unroll
        for (int kt = 0; kt < 4; kt++) {
            int r = kt * 16 + l16;
#pragma unroll
            for (int ks = 0; ks < 4; ks++) {
                bf16x8 kf = *(bf16x8*)&Ks[r * 128 + (((ks * 4 + lhi) ^ (r & 7)) << 3)];
                s[0][kt] = __builtin_amdgcn_mfma_f32_16x16x32_bf16(kf, qa[0][ks], s[0][kt], 0, 0, 0);
                s[1][kt] = __builtin_amdgcn_mfma_f32_16x16x32_bf16(kf, qa[1][ks], s[1][kt], 0, 0, 0);
            }
        }
        __builtin_amdgcn_s_setprio(0);

        float pm[2];
#pragma unroll
        for (int mt = 0; mt < 2; mt++) {
            float a = s[mt][0][0];
#pragma unroll
            for (int kt = 0; kt < 4; kt++)
#pragma unroll
                for (int rg = 0; rg < 4; rg++) a = fmaxf(a, s[mt][kt][rg]);
            a = fmaxf(a, __shfl_xor(a, 16));
            a = fmaxf(a, __shfl_xor(a, 32));
            pm[mt] = a;
        }
        bool need = (pm[0] > m_r[0] + 8.f) || (pm[1] > m_r[1] + 8.f);
        if (__any(need)) {
#pragma unroll
            for (int mt = 0; mt < 2; mt++) {
                float mn = fmaxf(m_r[mt], pm[mt]);
                float f = __builtin_amdgcn_exp2f(m_r[mt] - mn);
                m_r[mt] = mn;
                l_r[mt] *= f;
#pragma unroll
                for (int rg = 0; rg < 4; rg++) {
                    float ft = __shfl(f, lhi * 4 + rg);
#pragma unroll
                    for (int dt = 0; dt < 8; dt++) acc[mt][dt][rg] *= ft;
                }
            }
        }

#pragma unroll
        for (int mt = 0; mt < 2; mt++) {
            int row = mt * 16 + l16;
            int rsw = row & 7;
            float ls = 0.f;
#pragma unroll
            for (int kt = 0; kt < 4; kt++) {
                float p0 = __builtin_amdgcn_exp2f(s[mt][kt][0] - m_r[mt]);
                float p1 = __builtin_amdgcn_exp2f(s[mt][kt][1] - m_r[mt]);
                float p2 = __builtin_amdgcn_exp2f(s[mt][kt][2] - m_r[mt]);
                float p3 = __builtin_amdgcn_exp2f(s[mt][kt][3] - m_r[mt]);
                ls += (p0 + p1) + (p2 + p3);
                unsigned u01, u23;
                asm("v_cvt_pk_bf16_f32 %0, %1, %2" : "=v"(u01) : "v"(p0), "v"(p1));
                asm("v_cvt_pk_bf16_f32 %0, %1, %2" : "=v"(u23) : "v"(p2), "v"(p3));
                int slot = kt * 2 + (lhi >> 1);
                int base = row * 64 + ((slot ^ rsw) << 3) + (lhi & 1) * 4;
                *(unsigned*)&Pw[base] = u01;
                *(unsigned*)&Pw[base + 2] = u23;
            }
            l_r[mt] += ls;
        }
        asm volatile("s_waitcnt lgkmcnt(0)" ::: "memory");

        bf16x8 pa0[2], pa1[2];
#pragma unroll
        for (int mt = 0; mt < 2; mt++) {
            int row = mt * 16 + l16;
            pa0[mt] = *(bf16x8*)&Pw[row * 64 + ((lhi ^ (row & 7)) << 3)];
            pa1[mt] = *(bf16x8*)&Pw[row * 64 + (((4 + lhi) ^ (row & 7)) << 3)];
        }
        __builtin_amdgcn_s_setprio(1);
#pragma unroll
        for (int dt = 0; dt < 8; dt++) {
            int d = dt * 16 + l16;
            bf16x8 vb0 = *(bf16x8*)&Vt2[d * 64 + ((lhi ^ (d & 7)) << 3)];
            bf16x8 vb1 = *(bf16x8*)&Vt2[d * 64 + (((4 + lhi) ^ (d & 7)) << 3)];
            acc[0][dt] = __builtin_amdgcn_mfma_f32_16x16x32_bf16(pa0[0], vb0, acc[0][dt], 0, 0, 0);
            acc[0][dt] = __builtin_amdgcn_mfma_f32_16x16x32_bf16(pa1[0], vb1, acc[0][dt], 0, 0, 0);
            acc[1][dt] = __builtin_amdgcn_mfma_f32_16x16x32_bf16(pa0[1], vb0, acc[1][dt], 0, 0, 0);
            acc[1][dt] = __builtin_amdgcn_mfma_f32_16x16x32_bf16(pa1[1], vb1, acc[1][dt], 0, 0, 0);
        }
        __builtin_amdgcn_s_setprio(0);

        if (c < 15) {
#pragma unroll
            for (int jj = 0; jj < 4; jj++) {
                *(bf16x8*)&Ksn[(krow + jj * 16) * 128 + kls] = kpre[jj];
                *(bf16x8*)&Vtn[(vrow + jj * 32) * 64 + vls] = vpre[jj];
            }
        }
        __syncthreads();
    }

#pragma unroll
    for (int mt = 0; mt < 2; mt++) {
        float lt = l_r[mt];
        lt += __shfl_xor(lt, 16);
        lt += __shfl_xor(lt, 32);
        l_r[mt] = lt;
    }
    size_t obase = (size_t)(z >> 3) * 16384 + (size_t)(z & 7) * 2048;
#pragma unroll
    for (int mt = 0; mt < 2; mt++)
#pragma unroll
        for (int rg = 0; rg < 4; rg++) {
            float linv = 1.f / __shfl(l_r[mt], lhi * 4 + rg);
            int qrow = qt * 128 + w * 32 + mt * 16 + lhi * 4 + rg;
            unsigned short* orow = aout + (obase + qrow) * 512 + h * 128;
#pragma unroll
            for (int dt = 0; dt < 8; dt++)
                orow[dt * 16 + l16] = f2bf(acc[mt][dt][rg] * linv);
        }
}

// ---------------------------------------------------------------------------
// fused_s write + stats partials in one pass. grid (16, 8).
// ---------------------------------------------------------------------------
__global__ void k_fused_stats(const float* __restrict__ zc, const float* __restrict__ zl,
                              float* __restrict__ fs, float* __restrict__ part) {
    int c = blockIdx.x, b = blockIdx.y;
    int tid = threadIdx.x;
    int d = tid & 127, half = tid >> 7;
    size_t base0 = ((size_t)b * 2048 + c * 64) * 128;
    size_t base1 = ((size_t)b * 2048 + 1024 + c * 64) * 128;
    float s = 0.f, s2 = 0.f;
    for (int t = half; t < 64; t += 2) {
        float v = zc[base0 + t * 128 + d] + zc[base1 + t * 128 + d]
                + zl[base0 + t * 128 + d] + zl[base1 + t * 128 + d];
        fs[((size_t)b * 1024 + c * 64 + t) * 128 + d] = v;
        s += v; s2 += v * v;
    }
    __shared__ float ls[256], ls2[256];
    ls[tid] = s; ls2[tid] = s2;
    __syncthreads();
    if (tid < 128) {
        s = ls[tid] + ls[tid + 128];
        s2 = ls2[tid] + ls2[tid + 128];
        float* p = part + ((size_t)(b * 16 + c) * 2) * 128;
        p[d] = s; p[128 + d] = s2;
    }
}

// ---------------------------------------------------------------------------
extern "C" void kernel_launch(void* const* d_in, const int* in_sizes, int n_in,
                              void* d_out, int out_size, void* d_ws, size_t ws_size,
                              hipStream_t stream) {
    const float* cam_feat = (const float*)d_in[0];
    const float* lid_feat = (const float*)d_in[1];
    const float* pos      = (const float*)d_in[2];
    const float* conv_w   = (const float*)d_in[3];
    const float* convT_w  = (const float*)d_in[4];
    const float* lnq_g = (const float*)d_in[5];
    const float* lnq_b = (const float*)d_in[6];
    const float* wq    = (const float*)d_in[7];
    const float* lnk_g = (const float*)d_in[8];
    const float* lnk_b = (const float*)d_in[9];
    const float* wk    = (const float*)d_in[10];
    const float* lnv_g = (const float*)d_in[11];
    const float* lnv_b = (const float*)d_in[12];
    const float* wv    = (const float*)d_in[13];
    const float* proj_w = (const float*)d_in[14];
    const float* proj_b = (const float*)d_in[15];
    const float* pre_g = (const float*)d_in[16];
    const float* pre_b = (const float*)d_in[17];
    const float* mlp_w1 = (const float*)d_in[18];
    const float* mlp_b1 = (const float*)d_in[19];
    const float* mlp_w2 = (const float*)d_in[20];
    const float* mlp_b2 = (const float*)d_in[21];
    const float* post_g = (const float*)d_in[22];
    const float* post_b = (const float*)d_in[23];

    float* ws = (float*)d_ws;
    float* outp = (float*)d_out;

    // persistent buffers (floats)
    float* cam_eT  = ws + 0;               // 1,048,576
    float* lid_eT  = ws + 1048576;         // 1,048,576
    unsigned short* qbf16 = (unsigned short*)(ws + 2097152);   // 4,194,304 f
    float* z_cam   = ws + 6291456;         // 2,097,152
    float* z_lid   = ws + 8388608;         // 2,097,152
    float* fused_s = ws + 10485760;        // 1,048,576
    float* stats   = ws + 11534336;        // 16,384
    unsigned short* wbuf = (unsigned short*)(ws + 11550720);   // 196,608 f
    float* part    = ws + 11747328;        // 131,072
    float* mean_e  = ws + 11878400;        // 16,384
    float* rstd_e  = ws + 11894784;        // 16,384
    float* bvecs   = ws + 11911168;        // 1,536
    unsigned short* xcolT = (unsigned short*)(ws + 11912704);  // 4,194,304 f
    float* pool    = ws + 16107008;        // 16,777,216

    unsigned short* wqT   = wbuf + 0;
    unsigned short* wkT   = wbuf + 65536;
    unsigned short* wvT   = wbuf + 131072;
    unsigned short* projT = wbuf + 196608;
    unsigned short* m1T   = wbuf + 262144;
    unsigned short* m2T   = wbuf + 294912;
    unsigned short* ctT   = wbuf + 327680;

    float* meanA = stats + 0,    *rstdA = stats + 2048;
    float* meanF = stats + 4096, *rstdF = stats + 5120;

    // pool (timeline-overlapped)
    unsigned short* kbf16 = (unsigned short*)(pool + 0);        // 4,194,304 f
    unsigned short* vbfT  = (unsigned short*)(pool + 4194304);  // 4,194,304 f
    unsigned short* abuf  = (unsigned short*)(pool + 8388608);  // 8,388,608 f

    // 1/sqrt(128) * log2(e): attention softmax runs in the exp2 domain
    const float qscale = 0.12751744436f;

    // Weight prep + bias vectors (one launch)
    k_wtrans_all<<<390, TPB, 0, stream>>>(wq, wk, wv, proj_w, mlp_w1, mlp_w2, convT_w,
                                          lnq_g, lnk_g, lnv_g, lnq_b, lnk_b, lnv_b,
                                          wqT, wkT, wvT, projT, m1T, m2T, ctT, bvecs);

    // Stage A: stats + conv encoders (conv epilogue emits per-token LN stats)
    k_stats_cm<<<2048, TPB, 0, stream>>>(cam_feat, lid_feat, pos, meanA, rstdA);
    k_prep<<<dim3(32, 16), TPB, 0, stream>>>(cam_feat, lid_feat, pos, meanA, rstdA, xcolT);
    k_conv_gemm<<<dim3(16, 1, 16), TPB, 0, stream>>>(conv_w, xcolT, cam_eT, lid_eT,
                                                     mean_e, rstd_e);

    // Q/K/V; attention; fused tail (proj+preLN+mlp1+mlp2+postLN+stats)
    k_qkv_gemm<<<dim3(12, 128), TPB, 0, stream>>>(
        cam_eT, lid_eT, mean_e, rstd_e, wqT, wkT, wvT, qbf16, kbf16, vbfT,
        bvecs, qscale);
    k_attn_bf16<<<1024, TPB, 0, stream>>>(qbf16, kbf16, vbfT, abuf);
    k_tail_fused<<<512, TPB, 0, stream>>>(
        abuf, projT, m1T, m2T, cam_eT, lid_eT, proj_b, pre_g, pre_b,
        mlp_b1, mlp_b2, post_g, post_b, z_cam, z_lid, part);

    // Outputs
    k_stats_red2<<<16, 128, 0, stream>>>(part, stats + 6144, stats + 7168,
                                         stats + 8192, stats + 9216);
    k_fused_stats<<<dim3(16, 8), TPB, 0, stream>>>(z_cam, z_lid, fused_s, part + 65536);
    k_stats_red<<<8, 128, 0, stream>>>(part + 65536, meanF, rstdF, 16, 1024);
    k_convt_gemm<<<dim3(4, 40, 8), TPB, 0, stream>>>(fused_s, z_cam, z_lid, stats,
                                                     ctT, outp);
}